// Round 9
// baseline (218.231 us; speedup 1.0000x reference)
//
#include <hip/hip_runtime.h>
#include <hip/hip_bf16.h>

#define NN 6144
#define HEADS 4
#define DIN 256
#define DOUT 64

typedef __bf16 bf16_t;
typedef bf16_t bf16x8 __attribute__((ext_vector_type(8)));
typedef float f32x16 __attribute__((ext_vector_type(16)));
typedef float f32x4 __attribute__((ext_vector_type(4)));
typedef unsigned u32x4 __attribute__((ext_vector_type(4)));

#if __has_builtin(__builtin_amdgcn_exp2f)
#define EXP2(x) __builtin_amdgcn_exp2f(x)
#else
#define EXP2(x) exp2f(x)
#endif

static __device__ __forceinline__ f32x16 zero16() {
  f32x16 z;
#pragma unroll
  for (int i = 0; i < 16; ++i) z[i] = 0.0f;
  return z;
}

static __device__ __forceinline__ bf16x8 ldg8(const bf16_t* p) {
  return *reinterpret_cast<const bf16x8*>(p);
}

static __device__ __forceinline__ unsigned pk2(float a, float b) {
  union { bf16_t h[2]; unsigned u; } z;
  z.h[0] = (bf16_t)a;
  z.h[1] = (bf16_t)b;
  return z.u;
}

// v_permlane32_swap_b32: x.hi32lanes <-> y.lo32lanes
static __device__ __forceinline__ void pswap(unsigned& x, unsigned& y) {
  asm("v_permlane32_swap_b32 %0, %1" : "+v"(x), "+v"(y));
}

// async global->LDS, 16B per lane; dest = wave-uniform base + lane*16.
static __device__ __forceinline__ void gload_lds16(const float* g, float* lds) {
  __builtin_amdgcn_global_load_lds(
      (const __attribute__((address_space(1))) unsigned*)(uintptr_t)g,
      (__attribute__((address_space(3))) unsigned*)(unsigned)(uintptr_t)lds,
      16, 0, 0);
}

#define SCHED0() __builtin_amdgcn_sched_barrier(0)
#define VW(N)                                                   \
  asm volatile("s_waitcnt vmcnt(" #N ")" ::: "memory");         \
  SCHED0();

// ---------------- prep: h->bf16, W->bf16^T (Q-scale folded), zero out+denom
__global__ __launch_bounds__(256) void prep_kernel(
    const float* __restrict__ h, const float* __restrict__ WQ,
    const float* __restrict__ WK, const float* __restrict__ WV,
    bf16_t* __restrict__ hb, bf16_t* __restrict__ Wt,
    float* __restrict__ out, float* __restrict__ denom) {
  int stride = gridDim.x * blockDim.x;
  int idx = blockIdx.x * blockDim.x + threadIdx.x;
  for (int i = idx; i < HEADS * NN * DOUT; i += stride) out[i] = 0.0f;
  for (int i = idx; i < HEADS * NN; i += stride) denom[i] = 0.0f;
  for (int i = idx; i < NN * DIN; i += stride) hb[i] = (bf16_t)h[i];
  const float c2 = 0.0625f * 1.4426950408889634f;  // (1/sqrt(256)) * log2(e)
  for (int i = idx; i < 3 * HEADS * DOUT * DIN; i += stride) {
    int d = i & (DIN - 1);
    int o = (i >> 8) & (DOUT - 1);
    int hh = (i >> 14) & (HEADS - 1);
    int m = i >> 16;
    const float* W = (m == 0) ? WQ : (m == 1) ? WK : WV;
    float v = W[(hh * DIN + d) * DOUT + o];
    if (m == 0) v *= c2;
    Wt[i] = (bf16_t)v;  // Wt[m][hh][o][d]
  }
}

// ---------------- proj: Qb row-major [H][N][64]; Kf (A-frag) / Vf (B-frag).
__global__ __launch_bounds__(256) void proj_kernel(
    const bf16_t* __restrict__ hb, const bf16_t* __restrict__ Wt,
    const float* __restrict__ bQ, const float* __restrict__ bK,
    const float* __restrict__ bV,
    bf16_t* __restrict__ Qb, bf16_t* __restrict__ Kf, bf16_t* __restrict__ Vf) {
  const float c2 = 0.0625f * 1.4426950408889634f;
  int tid = threadIdx.x;
  int w = tid >> 6, l = tid & 63;
  int l31 = l & 31, lh = l >> 5;
  int hh = blockIdx.y;
  int n0 = blockIdx.x * 64;

#pragma unroll
  for (int s = 0; s < 3; ++s) {
    int t = w * 3 + s;  // 12 tiles: 0-3 Q, 4-7 K, 8-11 V
    if (t < 8) {
      int m = t >> 2;            // 0=Q, 1=K
      int rh = (t >> 1) & 1;     // row half (key half)
      int oh = t & 1;            // out-col half
      const bf16_t* arow = hb + (n0 + rh * 32 + l31) * DIN + 8 * lh;
      const bf16_t* brow = Wt + ((m * HEADS + hh) * DOUT + oh * 32 + l31) * DIN + 8 * lh;
      f32x16 acc = zero16();
#pragma unroll
      for (int kc = 0; kc < 16; ++kc)
        acc = __builtin_amdgcn_mfma_f32_32x32x16_bf16(ldg8(arow + kc * 16),
                                                      ldg8(brow + kc * 16), acc, 0, 0, 0);
      const float* bias = (m == 0) ? bQ : bK;
      float bv = bias[hh * DOUT + oh * 32 + l31];
      if (m == 0) {
        bv *= c2;
        bf16_t* outp = Qb + (size_t)(hh * NN + n0 + rh * 32) * DOUT + oh * 32 + l31;
#pragma unroll
        for (int r = 0; r < 16; ++r) {
          int q = (r & 3) + 8 * (r >> 2) + 4 * lh;
          outp[q * DOUT] = (bf16_t)(acc[r] + bv);
        }
      } else {
        int o = oh * 32 + l31;
        bf16_t* outp = Kf + (size_t)hh * 393216 + (n0 >> 6) * 4096 + rh * 2048 +
                       (o >> 4) * 512 + ((o >> 3) & 1) * 256 + (o & 7);
#pragma unroll
        for (int r = 0; r < 16; ++r) {
          int rr = (r & 3) + 8 * (r >> 2) + 4 * lh;  // key & 31
          outp[rr * 8] = (bf16_t)(acc[r] + bv);
        }
      }
    } else {
      int tt = t - 8;
      int oh = tt >> 1, nh = tt & 1;  // oh = d half, nh = key half
      const bf16_t* arow = Wt + ((2 * HEADS + hh) * DOUT + oh * 32 + l31) * DIN + 8 * lh;
      const bf16_t* brow = hb + (n0 + nh * 32 + l31) * DIN + 8 * lh;
      f32x16 acc = zero16();
#pragma unroll
      for (int kc = 0; kc < 16; ++kc)
        acc = __builtin_amdgcn_mfma_f32_32x32x16_bf16(ldg8(arow + kc * 16),
                                                      ldg8(brow + kc * 16), acc, 0, 0, 0);
      int k6 = nh * 32 + l31;
      bf16_t* outp = Vf + (size_t)hh * 393216 + (n0 >> 6) * 4096 + oh * 2048 +
                     (k6 >> 4) * 512 + ((k6 >> 3) & 1) * 256 + (k6 & 7);
#pragma unroll
      for (int r = 0; r < 16; ++r) {
        int rr = (r & 3) + 8 * (r >> 2) + 4 * lh;  // d & 31
        float bvv = bV[hh * DOUT + oh * 32 + rr];
        outp[rr * 8] = (bf16_t)(acc[r] + bvv);
      }
    }
  }
}

// ---- attn helpers --------------------------------------------------------

static __device__ __forceinline__ void kvload(bf16x8 (&KF)[8], bf16x8 (&VF)[8],
                                              const bf16_t* Kh, const bf16_t* Vh,
                                              int ck, int l) {
  const bf16_t* kb = Kh + (size_t)ck * 4096 + l * 8;
  const bf16_t* vb = Vh + (size_t)ck * 4096 + l * 8;
#pragma unroll
  for (int x = 0; x < 4; ++x) {
    KF[x] = ldg8(kb + x * 512);
    KF[4 + x] = ldg8(kb + 2048 + x * 512);
  }
#pragma unroll
  for (int x = 0; x < 4; ++x) {
    VF[x] = ldg8(vb + x * 512);
    VF[4 + x] = ldg8(vb + 2048 + x * 512);
  }
}

// stage 16 rows (r0..r0+15) of tile `tt` (256 keys) -- each instruction is
// ONE CONTIGUOUS 1-KB row burst (full DRAM page). Source pre-swizzled so the
// linear LDS row holds unit u at position u^(row&7).
static __device__ __forceinline__ void stage_half(const float* adjq, float* bufW,
                                                  int tt, int r0, int l) {
#pragma unroll
  for (int i = 0; i < 16; ++i) {
    int row = r0 + i;
    gload_lds16(adjq + (size_t)row * NN + tt * 256 + ((l ^ (row & 7)) << 2),
                bufW + row * 256);
  }
}

template <int S>
static __device__ __forceinline__ void compute_sub(
    const float* bufR, int l31, int lh, const bf16x8 (&KF)[8],
    const bf16x8 (&VF)[8], const bf16x8 (&qf)[4], f32x16& o0, f32x16& o1,
    float& sacc) {
  // adj readback: row = own q (l31); 16B-unit col c within the 256-key row
  f32x4 av[8];
#pragma unroll
  for (int t2 = 0; t2 < 2; ++t2)
#pragma unroll
    for (int g = 0; g < 4; ++g) {
      int c = 16 * S + 8 * t2 + 2 * g + lh;
      av[t2 * 4 + g] = *reinterpret_cast<const f32x4*>(
          bufR + l31 * 256 + ((c ^ (l31 & 7)) << 2));
    }

  // S^T = K * Q^T : row = key (reg), col = q (lane)
  f32x16 s0 = zero16(), s1 = zero16();
#pragma unroll
  for (int kc = 0; kc < 4; ++kc) {
    s0 = __builtin_amdgcn_mfma_f32_32x32x16_bf16(KF[kc], qf[kc], s0, 0, 0, 0);
    s1 = __builtin_amdgcn_mfma_f32_32x32x16_bf16(KF[4 + kc], qf[kc], s1, 0, 0, 0);
  }

  // P = exp2(S^T * adj); pack -> P-frag (A-operand); O = P^T * V
#pragma unroll
  for (int t2 = 0; t2 < 2; ++t2) {
    f32x16 st = t2 ? s1 : s0;
    float p[16];
#pragma unroll
    for (int r = 0; r < 16; ++r) {
      float pv = EXP2(st[r] * av[4 * t2 + (r >> 2)][r & 3]);
      p[r] = pv;
      sacc += pv;
    }
#pragma unroll
    for (int c2 = 0; c2 < 2; ++c2) {
      unsigned wA0 = pk2(p[8 * c2 + 0], p[8 * c2 + 1]);
      unsigned wB0 = pk2(p[8 * c2 + 2], p[8 * c2 + 3]);
      unsigned wA1 = pk2(p[8 * c2 + 4], p[8 * c2 + 5]);
      unsigned wB1 = pk2(p[8 * c2 + 6], p[8 * c2 + 7]);
      pswap(wA0, wA1);
      pswap(wB0, wB1);
      u32x4 pw;
      pw[0] = wA0; pw[1] = wB0; pw[2] = wA1; pw[3] = wB1;
      bf16x8 pb = __builtin_bit_cast(bf16x8, pw);
      int kc = 2 * t2 + c2;
      o0 = __builtin_amdgcn_mfma_f32_32x32x16_bf16(pb, VF[kc], o0, 0, 0, 0);
      o1 = __builtin_amdgcn_mfma_f32_32x32x16_bf16(pb, VF[4 + kc], o1, 0, 0, 0);
    }
  }
}

// ---------------- attention: 1-wave blocks; 32q x 256k LDS tiles (64 KB dbuf);
// 1-KB contiguous stage bursts; verified counted-vmcnt ledger, zero barriers.
// Per tile t: [KV,stA,W32][KV,W32,stB][W16,KV][KV,W16] -- every stage chunk
// drains >=2 subiters after issue and strictly before tile t+1's readback.
__global__ __launch_bounds__(64, 1) void attn_kernel(
    const float* __restrict__ adj, const bf16_t* __restrict__ Qb,
    const bf16_t* __restrict__ Kf, const bf16_t* __restrict__ Vf,
    float* __restrict__ out, float* __restrict__ denom) {
  __shared__ __align__(16) float tile[2][32][256];  // 64 KB double buffer

  int l = threadIdx.x;  // 0..63
  int l31 = l & 31, lh = l >> 5;

  // bijective XCD swizzle (1536 % 8 == 0): XCD x gets one (hh,ky) group
  // -> its K/V slice (~390 KB) stays L2-resident.
  int bid = blockIdx.x;
  int sb = (bid & 7) * 192 + (bid >> 3);
  int bx = sb % 192;       // q-tile
  int rem = sb / 192;      // 0..7
  int ky = rem & 1;        // key half
  int hh = rem >> 1;       // head
  int q0 = bx * 32;

  // Q as B-frag: col = q = l31, k = kc*16 + 8*lh + 0..7 (pre-scaled by c2)
  const bf16_t* Qrow = Qb + (size_t)(hh * NN + q0 + l31) * DOUT + 8 * lh;
  bf16x8 qf[4];
#pragma unroll
  for (int kc = 0; kc < 4; ++kc) qf[kc] = ldg8(Qrow + kc * 16);

  const bf16_t* Kh = Kf + (size_t)hh * 393216;
  const bf16_t* Vh = Vf + (size_t)hh * 393216;
  const float* adjq = adj + (size_t)(hh * NN + q0) * NN + ky * 3072;
  const int ckb = ky * 48;  // first 64-key chunk of this half

  f32x16 o0 = zero16(), o1 = zero16();
  float sacc = 0.0f;

  bf16x8 kfE[8], vfE[8], kfO[8], vfO[8];

  // ---- prologue: kv(0) + whole tile 0, drain everything once
  kvload(kfE, vfE, Kh, Vh, ckb + 0, l);
  SCHED0();
  stage_half(adjq, &tile[0][0][0], 0, 0, l);
  stage_half(adjq, &tile[0][0][0], 0, 16, l);
  SCHED0();
  VW(0)

  for (int t = 0; t < 12; ++t) {
    float* bufR = &tile[t & 1][0][0];
    float* bufW = &tile[(t + 1) & 1][0][0];
    int tt = (t + 1 < 12) ? t + 1 : 11;  // dummy re-stage on last tile
    int js = t * 4;

    // s=0: consume kvE
    kvload(kfO, vfO, Kh, Vh, ckb + js + 1, l);
    SCHED0();
    stage_half(adjq, bufW, tt, 0, l);
    SCHED0();
    VW(32)
    compute_sub<0>(bufR, l31, lh, kfE, vfE, qf, o0, o1, sacc);

    // s=1: consume kvO
    kvload(kfE, vfE, Kh, Vh, ckb + js + 2, l);
    SCHED0();
    VW(32)
    stage_half(adjq, bufW, tt, 16, l);
    SCHED0();
    compute_sub<1>(bufR, l31, lh, kfO, vfO, qf, o0, o1, sacc);

    // s=2: consume kvE
    VW(16)
    kvload(kfO, vfO, Kh, Vh, ckb + js + 3, l);
    SCHED0();
    compute_sub<2>(bufR, l31, lh, kfE, vfE, qf, o0, o1, sacc);

    // s=3: consume kvO
    kvload(kfE, vfE, Kh, Vh, ckb + ((js + 4 < 48) ? js + 4 : 47), l);
    SCHED0();
    VW(16)
    compute_sub<3>(bufR, l31, lh, kfO, vfO, qf, o0, o1, sacc);
  }

  // ---- epilogue: additive partials (no-max softmax) via atomicAdd.
  float stot = sacc + __shfl_xor(sacc, 32);
  if (l < 32) atomicAdd(&denom[hh * NN + q0 + l31], stot);
#pragma unroll
  for (int r = 0; r < 16; ++r) {
    int q = (r & 3) + 8 * (r >> 2) + 4 * lh;
    size_t base = (size_t)(hh * NN + q0 + q) * DOUT;
    atomicAdd(&out[base + l31], o0[r]);
    atomicAdd(&out[base + 32 + l31], o1[r]);
  }
}

// ---------------- normalize: out /= denom, float4, exact coverage
__global__ __launch_bounds__(256) void norm_kernel(
    float* __restrict__ out, const float* __restrict__ denom) {
  int i = blockIdx.x * 256 + threadIdx.x;  // float4 index
  float dn = denom[i >> 4];
  f32x4 v = reinterpret_cast<f32x4*>(out)[i];
  float inv = 1.0f / dn;
#pragma unroll
  for (int j = 0; j < 4; ++j) v[j] *= inv;
  reinterpret_cast<f32x4*>(out)[i] = v;
}

extern "C" void kernel_launch(void* const* d_in, const int* in_sizes, int n_in,
                              void* d_out, int out_size, void* d_ws, size_t ws_size,
                              hipStream_t stream) {
  const float* adj = (const float*)d_in[0];
  const float* h   = (const float*)d_in[1];
  const float* WQ  = (const float*)d_in[2];
  const float* bQ  = (const float*)d_in[3];
  const float* WK  = (const float*)d_in[4];
  const float* bK  = (const float*)d_in[5];
  const float* WV  = (const float*)d_in[6];
  const float* bV  = (const float*)d_in[7];
  float* out = (float*)d_out;

  if (ws_size < 13074432) return;  // ~12.5 MB scratch

  char* ws = (char*)d_ws;
  bf16_t* hb    = (bf16_t*)ws;                 // [N][256] bf16           3,145,728 B
  bf16_t* Wt    = (bf16_t*)(ws + 3145728);     // [3][H][64][256] bf16      393,216 B
  bf16_t* Qb    = (bf16_t*)(ws + 3538944);     // [H][N][64] bf16 (scaled)3,145,728 B
  bf16_t* Kf    = (bf16_t*)(ws + 6684672);     // [H] K fragments         3,145,728 B
  bf16_t* Vf    = (bf16_t*)(ws + 9830400);     // [H] V fragments         3,145,728 B
  float*  denom = (float*)(ws + 12976128);     // [H][N] f32                 98,304 B

  prep_kernel<<<1024, 256, 0, stream>>>(h, WQ, WK, WV, hb, Wt, out, denom);
  proj_kernel<<<dim3(96, 4), 256, 0, stream>>>(hb, Wt, bQ, bK, bV, Qb, Kf, Vf);
  attn_kernel<<<1536, 64, 0, stream>>>(adj, Qb, Kf, Vf, out, denom);
  norm_kernel<<<1536, 256, 0, stream>>>(out, denom);
}

// Round 10
// 182.760 us; speedup vs baseline: 1.1941x; 1.1941x over previous
//
#include <hip/hip_runtime.h>
#include <hip/hip_bf16.h>

#define NN 6144
#define HEADS 4
#define DIN 256
#define DOUT 64

typedef __bf16 bf16_t;
typedef bf16_t bf16x8 __attribute__((ext_vector_type(8)));
typedef float f32x16 __attribute__((ext_vector_type(16)));
typedef float f32x4 __attribute__((ext_vector_type(4)));
typedef unsigned u32x4 __attribute__((ext_vector_type(4)));

#if __has_builtin(__builtin_amdgcn_exp2f)
#define EXP2(x) __builtin_amdgcn_exp2f(x)
#else
#define EXP2(x) exp2f(x)
#endif

static __device__ __forceinline__ f32x16 zero16() {
  f32x16 z;
#pragma unroll
  for (int i = 0; i < 16; ++i) z[i] = 0.0f;
  return z;
}

static __device__ __forceinline__ bf16x8 ldg8(const bf16_t* p) {
  return *reinterpret_cast<const bf16x8*>(p);
}

// pack two f32 -> one u32 of 2 bf16 (element 0 in low half)
static __device__ __forceinline__ unsigned pk2(float a, float b) {
  union { bf16_t h[2]; unsigned u; } z;
  z.h[0] = (bf16_t)a;
  z.h[1] = (bf16_t)b;
  return z.u;
}

// v_permlane32_swap_b32: x.hi32lanes <-> y.lo32lanes
static __device__ __forceinline__ void pswap(unsigned& x, unsigned& y) {
  asm("v_permlane32_swap_b32 %0, %1" : "+v"(x), "+v"(y));
}

// async global->LDS, 16B per lane. LDS dest = wave-uniform base + lane*16.
// NT variant: aux=2 (SLC/NT) marks the read-once adj stream non-temporal so
// it doesn't evict the K/V working set from the XCD's L2.
static __device__ __forceinline__ void gload_lds16_nt(const float* g, float* lds) {
  __builtin_amdgcn_global_load_lds(
      (const __attribute__((address_space(1))) unsigned*)(uintptr_t)g,
      (__attribute__((address_space(3))) unsigned*)(unsigned)(uintptr_t)lds,
      16, 0, 2);
}

// ---------------- prep: h -> bf16, W -> transposed bf16 (scale folded into WQ)
__global__ __launch_bounds__(256) void prep_kernel(
    const float* __restrict__ h, const float* __restrict__ WQ,
    const float* __restrict__ WK, const float* __restrict__ WV,
    bf16_t* __restrict__ hb, bf16_t* __restrict__ Wt) {
  int stride = gridDim.x * blockDim.x;
  int idx = blockIdx.x * blockDim.x + threadIdx.x;
  for (int i = idx; i < NN * DIN; i += stride)
    hb[i] = (bf16_t)h[i];
  const float c2 = 0.0625f * 1.4426950408889634f;  // (1/sqrt(256)) * log2(e)
  for (int i = idx; i < 3 * HEADS * DOUT * DIN; i += stride) {
    int d = i & (DIN - 1);
    int o = (i >> 8) & (DOUT - 1);
    int hh = (i >> 14) & (HEADS - 1);
    int m = i >> 16;
    const float* W = (m == 0) ? WQ : (m == 1) ? WK : WV;
    float v = W[(hh * DIN + d) * DOUT + o];
    if (m == 0) v *= c2;
    Wt[i] = (bf16_t)v;  // Wt[m][hh][o][d]
  }
}

// ---------------- proj: Qb row-major [H][N][64]; Kf/Vf in MFMA-fragment order.
__global__ __launch_bounds__(256) void proj_kernel(
    const bf16_t* __restrict__ hb, const bf16_t* __restrict__ Wt,
    const float* __restrict__ bQ, const float* __restrict__ bK,
    const float* __restrict__ bV,
    bf16_t* __restrict__ Qb, bf16_t* __restrict__ Kf, bf16_t* __restrict__ Vf) {
  const float c2 = 0.0625f * 1.4426950408889634f;
  int tid = threadIdx.x;
  int w = tid >> 6, l = tid & 63;
  int l31 = l & 31, lh = l >> 5;
  int hh = blockIdx.y;
  int n0 = blockIdx.x * 64;

#pragma unroll
  for (int s = 0; s < 3; ++s) {
    int t = w * 3 + s;  // 12 tiles: 0-3 Q, 4-7 K, 8-11 V
    if (t < 8) {
      int m = t >> 2;            // 0=Q, 1=K
      int rh = (t >> 1) & 1;     // row half (key half)
      int oh = t & 1;            // out-col half
      const bf16_t* arow = hb + (n0 + rh * 32 + l31) * DIN + 8 * lh;
      const bf16_t* brow = Wt + ((m * HEADS + hh) * DOUT + oh * 32 + l31) * DIN + 8 * lh;
      f32x16 acc = zero16();
#pragma unroll
      for (int kc = 0; kc < 16; ++kc)
        acc = __builtin_amdgcn_mfma_f32_32x32x16_bf16(ldg8(arow + kc * 16),
                                                      ldg8(brow + kc * 16), acc, 0, 0, 0);
      const float* bias = (m == 0) ? bQ : bK;
      float bv = bias[hh * DOUT + oh * 32 + l31];
      if (m == 0) {
        bv *= c2;
        bf16_t* outp = Qb + (size_t)(hh * NN + n0 + rh * 32) * DOUT + oh * 32 + l31;
#pragma unroll
        for (int r = 0; r < 16; ++r) {
          int q = (r & 3) + 8 * (r >> 2) + 4 * lh;
          outp[q * DOUT] = (bf16_t)(acc[r] + bv);
        }
      } else {
        int o = oh * 32 + l31;
        bf16_t* outp = Kf + (size_t)hh * 393216 + (n0 >> 6) * 4096 + rh * 2048 +
                       (o >> 4) * 512 + ((o >> 3) & 1) * 256 + (o & 7);
#pragma unroll
        for (int r = 0; r < 16; ++r) {
          int rr = (r & 3) + 8 * (r >> 2) + 4 * lh;  // key & 31
          outp[rr * 8] = (bf16_t)(acc[r] + bv);
        }
      }
    } else {
      int tt = t - 8;
      int oh = tt >> 1, nh = tt & 1;  // oh = d half, nh = key half
      const bf16_t* arow = Wt + ((2 * HEADS + hh) * DOUT + oh * 32 + l31) * DIN + 8 * lh;
      const bf16_t* brow = hb + (n0 + nh * 32 + l31) * DIN + 8 * lh;
      f32x16 acc = zero16();
#pragma unroll
      for (int kc = 0; kc < 16; ++kc)
        acc = __builtin_amdgcn_mfma_f32_32x32x16_bf16(ldg8(arow + kc * 16),
                                                      ldg8(brow + kc * 16), acc, 0, 0, 0);
      int k6 = nh * 32 + l31;
      bf16_t* outp = Vf + (size_t)hh * 393216 + (n0 >> 6) * 4096 + oh * 2048 +
                     (k6 >> 4) * 512 + ((k6 >> 3) & 1) * 256 + (k6 & 7);
#pragma unroll
      for (int r = 0; r < 16; ++r) {
        int rr = (r & 3) + 8 * (r >> 2) + 4 * lh;  // d & 31
        float bvv = bV[hh * DOUT + oh * 32 + rr];
        outp[rr * 8] = (bf16_t)(acc[r] + bvv);
      }
    }
  }
}

// ---------------- attention: r6 structure (counted vmcnt, WAR-safe stage) +
// XCD head-affinity swizzle (K/V L2-resident per XCD) + NT adj stream.
__global__ __launch_bounds__(256, 2) void attn_kernel(
    const float* __restrict__ adj, const bf16_t* __restrict__ Qb,
    const bf16_t* __restrict__ Kf, const bf16_t* __restrict__ Vf,
    float* __restrict__ out) {
  __shared__ __align__(16) float smem[2][32][256];  // 64 KB; reused for epilogue

  int tid = threadIdx.x;
  int w = tid >> 6, l = tid & 63;
  int l31 = l & 31, lh = l >> 5;

  // bijective XCD swizzle (768 % 8 == 0): XCD k owns work-ids k*96..k*96+95 =
  // half of one head -> K/V working set 1.5 MB, L2-resident per XCD; adj
  // region contiguous ~75 MB per XCD.
  int bid = blockIdx.x;
  int work = (bid & 7) * 96 + (bid >> 3);
  int hh = work / 192;
  int q0 = (work % 192) * 32;

  // Q as B-fragment: col = q = l31, k = kc*16 + 8*lh + 0..7  (pre-scaled by c2)
  const bf16_t* Qrow = Qb + (size_t)(hh * NN + q0 + l31) * DOUT + 8 * lh;
  bf16x8 qf[4];
#pragma unroll
  for (int kc = 0; kc < 4; ++kc) qf[kc] = ldg8(Qrow + kc * 16);

  const bf16_t* Kh = Kf + (size_t)hh * 393216;
  const bf16_t* Vh = Vf + (size_t)hh * 393216;
  const float* adjq = adj + (size_t)hh * NN * NN + (size_t)q0 * NN;

  f32x16 o0 = zero16(), o1 = zero16();
  float sacc = 0.0f;

  // prologue: stage adj tile 0 into buf 0 (wave w stages rows 8w..8w+7;
  // each instruction = one contiguous 1-KB row; source chunk pre-swizzled
  // so the LDS readback swizzle is consistent)
#pragma unroll
  for (int i = 0; i < 8; ++i) {
    int row = 8 * w + i;
    gload_lds16_nt(adjq + (size_t)row * NN + ((l ^ i) << 2), &smem[0][row][0]);
  }

  for (int it = 0; it < 24; ++it) {
    int cur = it & 1;
    int chunk = it * 4 + w;  // this wave's 64-key chunk

    // ---- K/V fragments first (16 VMEM; stay in flight across the wait below)
    const bf16_t* kbase = Kh + (size_t)chunk * 4096 + l * 8;
    const bf16_t* vbase = Vh + (size_t)chunk * 4096 + l * 8;
    bf16x8 kf[8], vf[8];
#pragma unroll
    for (int x = 0; x < 4; ++x) {
      kf[x] = ldg8(kbase + x * 512);
      kf[4 + x] = ldg8(kbase + 2048 + x * 512);
    }
#pragma unroll
    for (int x = 0; x < 4; ++x) {
      vf[x] = ldg8(vbase + x * 512);
      vf[4 + x] = ldg8(vbase + 2048 + x * 512);
    }
    __builtin_amdgcn_sched_barrier(0);  // all 16 K/V issued before the wait

    // ---- wait for stage(it) (oldest 8 outstanding), keep K/V in flight
    asm volatile("s_waitcnt vmcnt(16)" ::: "memory");
    __builtin_amdgcn_sched_barrier(0);
    __builtin_amdgcn_s_barrier();
    __builtin_amdgcn_sched_barrier(0);

    // ---- stage next adj tile AFTER the barrier (WAR-safe). Dummy re-stage of
    // tile 23 on the last iter keeps counts uniform; drained before epilogue.
    int nt = (it + 1 < 24) ? it + 1 : 23;
#pragma unroll
    for (int i = 0; i < 8; ++i) {
      int row = 8 * w + i;
      gload_lds16_nt(adjq + (size_t)row * NN + nt * 256 + ((l ^ i) << 2),
                     &smem[cur ^ 1][row][0]);
    }
    __builtin_amdgcn_sched_barrier(0);

    // ---- adj readback: row = own q (l31), swizzled chunk
    f32x4 av[8];
#pragma unroll
    for (int t2 = 0; t2 < 2; ++t2)
#pragma unroll
      for (int g = 0; g < 4; ++g) {
        int c = 16 * w + 8 * t2 + 2 * g + lh;
        av[t2 * 4 + g] =
            *reinterpret_cast<const f32x4*>(&smem[cur][l31][(c ^ (l31 & 7)) << 2]);
      }

    // ---- S^T = K · Q^T : row = key (reg), col = q (lane)
    f32x16 s0 = zero16(), s1 = zero16();
#pragma unroll
    for (int kc = 0; kc < 4; ++kc) {
      s0 = __builtin_amdgcn_mfma_f32_32x32x16_bf16(kf[kc], qf[kc], s0, 0, 0, 0);
      s1 = __builtin_amdgcn_mfma_f32_32x32x16_bf16(kf[4 + kc], qf[kc], s1, 0, 0, 0);
    }

    // ---- P = exp2(S^T * adj); pack + permlane32_swap into PV B-frags; PV MFMA
#pragma unroll
    for (int t2 = 0; t2 < 2; ++t2) {
      f32x16 st = t2 ? s1 : s0;
      float p[16];
#pragma unroll
      for (int r = 0; r < 16; ++r) {
        float pv = EXP2(st[r] * av[4 * t2 + (r >> 2)][r & 3]);
        p[r] = pv;
        sacc += pv;
      }
#pragma unroll
      for (int c = 0; c < 2; ++c) {
        unsigned wA0 = pk2(p[8 * c + 0], p[8 * c + 1]);
        unsigned wB0 = pk2(p[8 * c + 2], p[8 * c + 3]);
        unsigned wA1 = pk2(p[8 * c + 4], p[8 * c + 5]);
        unsigned wB1 = pk2(p[8 * c + 6], p[8 * c + 7]);
        pswap(wA0, wA1);
        pswap(wB0, wB1);
        u32x4 pw;
        pw[0] = wA0; pw[1] = wB0; pw[2] = wA1; pw[3] = wB1;
        bf16x8 pb = __builtin_bit_cast(bf16x8, pw);
        int kc = 2 * t2 + c;
        o0 = __builtin_amdgcn_mfma_f32_32x32x16_bf16(vf[kc], pb, o0, 0, 0, 0);
        o1 = __builtin_amdgcn_mfma_f32_32x32x16_bf16(vf[4 + kc], pb, o1, 0, 0, 0);
      }
    }
    // next iteration's vmcnt(16)+s_barrier is the sync point; stage(it+1)
    // writes only buf[cur^1], which nobody reads in this window.
  }

  // drain the dummy stage before smem is reused, then block-wide sync
  asm volatile("s_waitcnt vmcnt(0)" ::: "memory");
  __syncthreads();

  // ---- epilogue: reuse smem for cross-wave combine
  float stot = sacc + __shfl_xor(sacc, 32);
  float* opart = &smem[0][0][0];        // [4][64][32]
  float* ssum = &smem[0][0][0] + 8192;  // [4][32]
  if (l < 32) ssum[w * 32 + l31] = stot;
#pragma unroll
  for (int r = 0; r < 16; ++r) {
    int d = (r & 3) + 8 * (r >> 2) + 4 * lh;
    opart[w * 2048 + d * 32 + l31] = o0[r];
    opart[w * 2048 + (32 + d) * 32 + l31] = o1[r];
  }
  __syncthreads();

#pragma unroll
  for (int k = 0; k < 8; ++k) {
    int idx = k * 256 + tid;
    int q = idx & 31, d = idx >> 5;
    float s = ssum[q] + ssum[32 + q] + ssum[64 + q] + ssum[96 + q];
    float ov = opart[d * 32 + q] + opart[2048 + d * 32 + q] +
               opart[4096 + d * 32 + q] + opart[6144 + d * 32 + q];
    out[(size_t)(hh * NN + q0 + q) * DOUT + d] = ov / s;
  }
}

extern "C" void kernel_launch(void* const* d_in, const int* in_sizes, int n_in,
                              void* d_out, int out_size, void* d_ws, size_t ws_size,
                              hipStream_t stream) {
  const float* adj = (const float*)d_in[0];
  const float* h   = (const float*)d_in[1];
  const float* WQ  = (const float*)d_in[2];
  const float* bQ  = (const float*)d_in[3];
  const float* WK  = (const float*)d_in[4];
  const float* bK  = (const float*)d_in[5];
  const float* WV  = (const float*)d_in[6];
  const float* bV  = (const float*)d_in[7];
  float* out = (float*)d_out;

  if (ws_size < 12976128) return;  // need ~12.4 MB scratch

  char* ws = (char*)d_ws;
  bf16_t* hb = (bf16_t*)ws;                 // [N][256] bf16            3,145,728 B
  bf16_t* Wt = (bf16_t*)(ws + 3145728);     // [3][H][64][256] bf16       393,216 B
  bf16_t* Qb = (bf16_t*)(ws + 3538944);     // [H][N][64] bf16 (scaled) 3,145,728 B
  bf16_t* Kf = (bf16_t*)(ws + 6684672);     // [H] K fragments          3,145,728 B
  bf16_t* Vf = (bf16_t*)(ws + 9830400);     // [H] V fragments          3,145,728 B

  prep_kernel<<<1024, 256, 0, stream>>>(h, WQ, WK, WV, hb, Wt);
  proj_kernel<<<dim3(96, 4), 256, 0, stream>>>(hb, Wt, bQ, bK, bV, Qb, Kf, Vf);
  attn_kernel<<<768, 256, 0, stream>>>(adj, Qb, Kf, Vf, out);
}

// Round 11
// 175.959 us; speedup vs baseline: 1.2402x; 1.0386x over previous
//
#include <hip/hip_runtime.h>
#include <hip/hip_bf16.h>

#define NN 6144
#define HEADS 4
#define DIN 256
#define DOUT 64

typedef __bf16 bf16_t;
typedef bf16_t bf16x8 __attribute__((ext_vector_type(8)));
typedef float f32x16 __attribute__((ext_vector_type(16)));
typedef float f32x4 __attribute__((ext_vector_type(4)));
typedef unsigned u32x4 __attribute__((ext_vector_type(4)));

#if __has_builtin(__builtin_amdgcn_exp2f)
#define EXP2(x) __builtin_amdgcn_exp2f(x)
#else
#define EXP2(x) exp2f(x)
#endif

static __device__ __forceinline__ f32x16 zero16() {
  f32x16 z;
#pragma unroll
  for (int i = 0; i < 16; ++i) z[i] = 0.0f;
  return z;
}

static __device__ __forceinline__ bf16x8 ldg8(const bf16_t* p) {
  return *reinterpret_cast<const bf16x8*>(p);
}

// pack two f32 -> one u32 of 2 bf16 (element 0 in low half)
static __device__ __forceinline__ unsigned pk2(float a, float b) {
  union { bf16_t h[2]; unsigned u; } z;
  z.h[0] = (bf16_t)a;
  z.h[1] = (bf16_t)b;
  return z.u;
}

// v_permlane32_swap_b32: x.hi32lanes <-> y.lo32lanes
static __device__ __forceinline__ void pswap(unsigned& x, unsigned& y) {
  asm("v_permlane32_swap_b32 %0, %1" : "+v"(x), "+v"(y));
}

// non-temporal 16B read (read-once adj stream; don't evict K/V from L2)
static __device__ __forceinline__ f32x4 ldnt4(const float* p) {
  return __builtin_nontemporal_load(reinterpret_cast<const f32x4*>(p));
}

#define SCHED0() __builtin_amdgcn_sched_barrier(0)

// ---------------- prep: h -> bf16, W -> transposed bf16 (scale folded into WQ)
__global__ __launch_bounds__(256) void prep_kernel(
    const float* __restrict__ h, const float* __restrict__ WQ,
    const float* __restrict__ WK, const float* __restrict__ WV,
    bf16_t* __restrict__ hb, bf16_t* __restrict__ Wt) {
  int stride = gridDim.x * blockDim.x;
  int idx = blockIdx.x * blockDim.x + threadIdx.x;
  for (int i = idx; i < NN * DIN; i += stride)
    hb[i] = (bf16_t)h[i];
  const float c2 = 0.0625f * 1.4426950408889634f;  // (1/sqrt(256)) * log2(e)
  for (int i = idx; i < 3 * HEADS * DOUT * DIN; i += stride) {
    int d = i & (DIN - 1);
    int o = (i >> 8) & (DOUT - 1);
    int hh = (i >> 14) & (HEADS - 1);
    int m = i >> 16;
    const float* W = (m == 0) ? WQ : (m == 1) ? WK : WV;
    float v = W[(hh * DIN + d) * DOUT + o];
    if (m == 0) v *= c2;
    Wt[i] = (bf16_t)v;  // Wt[m][hh][o][d]
  }
}

// ---------------- proj: Qb row-major [H][N][64]; Kf/Vf in MFMA-fragment order.
__global__ __launch_bounds__(256) void proj_kernel(
    const bf16_t* __restrict__ hb, const bf16_t* __restrict__ Wt,
    const float* __restrict__ bQ, const float* __restrict__ bK,
    const float* __restrict__ bV,
    bf16_t* __restrict__ Qb, bf16_t* __restrict__ Kf, bf16_t* __restrict__ Vf) {
  const float c2 = 0.0625f * 1.4426950408889634f;
  int tid = threadIdx.x;
  int w = tid >> 6, l = tid & 63;
  int l31 = l & 31, lh = l >> 5;
  int hh = blockIdx.y;
  int n0 = blockIdx.x * 64;

#pragma unroll
  for (int s = 0; s < 3; ++s) {
    int t = w * 3 + s;  // 12 tiles: 0-3 Q, 4-7 K, 8-11 V
    if (t < 8) {
      int m = t >> 2;            // 0=Q, 1=K
      int rh = (t >> 1) & 1;     // row half (key half)
      int oh = t & 1;            // out-col half
      const bf16_t* arow = hb + (n0 + rh * 32 + l31) * DIN + 8 * lh;
      const bf16_t* brow = Wt + ((m * HEADS + hh) * DOUT + oh * 32 + l31) * DIN + 8 * lh;
      f32x16 acc = zero16();
#pragma unroll
      for (int kc = 0; kc < 16; ++kc)
        acc = __builtin_amdgcn_mfma_f32_32x32x16_bf16(ldg8(arow + kc * 16),
                                                      ldg8(brow + kc * 16), acc, 0, 0, 0);
      const float* bias = (m == 0) ? bQ : bK;
      float bv = bias[hh * DOUT + oh * 32 + l31];
      if (m == 0) {
        bv *= c2;
        bf16_t* outp = Qb + (size_t)(hh * NN + n0 + rh * 32) * DOUT + oh * 32 + l31;
#pragma unroll
        for (int r = 0; r < 16; ++r) {
          int q = (r & 3) + 8 * (r >> 2) + 4 * lh;
          outp[q * DOUT] = (bf16_t)(acc[r] + bv);
        }
      } else {
        int o = oh * 32 + l31;
        bf16_t* outp = Kf + (size_t)hh * 393216 + (n0 >> 6) * 4096 + rh * 2048 +
                       (o >> 4) * 512 + ((o >> 3) & 1) * 256 + (o & 7);
#pragma unroll
        for (int r = 0; r < 16; ++r) {
          int rr = (r & 3) + 8 * (r >> 2) + 4 * lh;  // key & 31
          outp[rr * 8] = (bf16_t)(acc[r] + bv);
        }
      }
    } else {
      int tt = t - 8;
      int oh = tt >> 1, nh = tt & 1;  // oh = d half, nh = key half
      const bf16_t* arow = Wt + ((2 * HEADS + hh) * DOUT + oh * 32 + l31) * DIN + 8 * lh;
      const bf16_t* brow = hb + (n0 + nh * 32 + l31) * DIN + 8 * lh;
      f32x16 acc = zero16();
#pragma unroll
      for (int kc = 0; kc < 16; ++kc)
        acc = __builtin_amdgcn_mfma_f32_32x32x16_bf16(ldg8(arow + kc * 16),
                                                      ldg8(brow + kc * 16), acc, 0, 0, 0);
      int k6 = nh * 32 + l31;
      bf16_t* outp = Vf + (size_t)hh * 393216 + (n0 >> 6) * 4096 + oh * 2048 +
                     (k6 >> 4) * 512 + ((k6 >> 3) & 1) * 256 + (k6 & 7);
#pragma unroll
      for (int r = 0; r < 16; ++r) {
        int rr = (r & 3) + 8 * (r >> 2) + 4 * lh;  // d & 31
        float bvv = bV[hh * DOUT + oh * 32 + rr];
        outp[rr * 8] = (bf16_t)(acc[r] + bvv);
      }
    }
  }
}

// ---------------- attention: r10 structure, but adj staged via REGISTERS
// (T14: global->reg (NT) issued early, ds_write late) instead of
// global_load_lds. Single-variable test of the direct-to-LDS path.
__global__ __launch_bounds__(256, 2) void attn_kernel(
    const float* __restrict__ adj, const bf16_t* __restrict__ Qb,
    const bf16_t* __restrict__ Kf, const bf16_t* __restrict__ Vf,
    float* __restrict__ out) {
  __shared__ __align__(16) float smem[2][32][256];  // 64 KB; reused for epilogue

  int tid = threadIdx.x;
  int w = tid >> 6, l = tid & 63;
  int l31 = l & 31, lh = l >> 5;

  // bijective XCD swizzle (768 % 8 == 0): XCD k owns work-ids k*96..k*96+95 =
  // half of one head -> K/V working set 1.5 MB, L2-resident per XCD.
  int bid = blockIdx.x;
  int work = (bid & 7) * 96 + (bid >> 3);
  int hh = work / 192;
  int q0 = (work % 192) * 32;

  // Q as B-fragment: col = q = l31, k = kc*16 + 8*lh + 0..7  (pre-scaled by c2)
  const bf16_t* Qrow = Qb + (size_t)(hh * NN + q0 + l31) * DOUT + 8 * lh;
  bf16x8 qf[4];
#pragma unroll
  for (int kc = 0; kc < 4; ++kc) qf[kc] = ldg8(Qrow + kc * 16);

  const bf16_t* Kh = Kf + (size_t)hh * 393216;
  const bf16_t* Vh = Vf + (size_t)hh * 393216;
  const float* adjq = adj + (size_t)hh * NN * NN + (size_t)q0 * NN;

  f32x16 o0 = zero16(), o1 = zero16();
  float sacc = 0.0f;

  f32x4 areg[8];  // in-flight adj tile (wave w owns rows 8w..8w+7)

  // ---- prologue: tile 0 -> regs -> LDS buf 0 (swizzle applied on ds_write:
  // LDS[row][u] = G[row][u ^ (row&7)], matching the readback XOR)
#pragma unroll
  for (int i = 0; i < 8; ++i) {
    int row = 8 * w + i;
    areg[i] = ldnt4(adjq + (size_t)row * NN + ((l ^ i) << 2));
  }
  asm volatile("s_waitcnt vmcnt(0)" ::: "memory");
  SCHED0();
#pragma unroll
  for (int i = 0; i < 8; ++i) {
    int row = 8 * w + i;
    *reinterpret_cast<f32x4*>(&smem[0][row][l << 2]) = areg[i];
  }
  asm volatile("s_waitcnt lgkmcnt(0)" ::: "memory");
  SCHED0();
  __builtin_amdgcn_s_barrier();
  SCHED0();

  for (int it = 0; it < 24; ++it) {
    int cur = it & 1;
    int chunk = it * 4 + w;  // this wave's 64-key chunk

    // ---- K/V fragments first (16 VMEM)
    const bf16_t* kbase = Kh + (size_t)chunk * 4096 + l * 8;
    const bf16_t* vbase = Vh + (size_t)chunk * 4096 + l * 8;
    bf16x8 kf[8], vf[8];
#pragma unroll
    for (int x = 0; x < 4; ++x) {
      kf[x] = ldg8(kbase + x * 512);
      kf[4 + x] = ldg8(kbase + 2048 + x * 512);
    }
#pragma unroll
    for (int x = 0; x < 4; ++x) {
      vf[x] = ldg8(vbase + x * 512);
      vf[4 + x] = ldg8(vbase + 2048 + x * 512);
    }
    SCHED0();

    // ---- issue adj tile(it+1) into registers (8 VMEM, newest; the compiler's
    // K/V waits (vmcnt>=8) never drain these). Pre-swizzled source so the
    // later linear ds_write yields LDS[row][u] = G[row][u^(row&7)].
    int nt = (it + 1 < 24) ? it + 1 : 23;
#pragma unroll
    for (int i = 0; i < 8; ++i) {
      int row = 8 * w + i;
      areg[i] = ldnt4(adjq + (size_t)row * NN + nt * 256 + ((l ^ i) << 2));
    }
    SCHED0();

    // ---- adj readback: row = own q (l31), swizzled chunk
    f32x4 av[8];
#pragma unroll
    for (int t2 = 0; t2 < 2; ++t2)
#pragma unroll
      for (int g = 0; g < 4; ++g) {
        int c = 16 * w + 8 * t2 + 2 * g + lh;
        av[t2 * 4 + g] =
            *reinterpret_cast<const f32x4*>(&smem[cur][l31][(c ^ (l31 & 7)) << 2]);
      }

    // ---- S^T = K · Q^T : row = key (reg), col = q (lane)
    f32x16 s0 = zero16(), s1 = zero16();
#pragma unroll
    for (int kc = 0; kc < 4; ++kc) {
      s0 = __builtin_amdgcn_mfma_f32_32x32x16_bf16(kf[kc], qf[kc], s0, 0, 0, 0);
      s1 = __builtin_amdgcn_mfma_f32_32x32x16_bf16(kf[4 + kc], qf[kc], s1, 0, 0, 0);
    }

    // ---- P = exp2(S^T * adj); pack + permlane32_swap into PV B-frags; PV MFMA
#pragma unroll
    for (int t2 = 0; t2 < 2; ++t2) {
      f32x16 st = t2 ? s1 : s0;
      float p[16];
#pragma unroll
      for (int r = 0; r < 16; ++r) {
        float pv = EXP2(st[r] * av[4 * t2 + (r >> 2)][r & 3]);
        p[r] = pv;
        sacc += pv;
      }
#pragma unroll
      for (int c = 0; c < 2; ++c) {
        unsigned wA0 = pk2(p[8 * c + 0], p[8 * c + 1]);
        unsigned wB0 = pk2(p[8 * c + 2], p[8 * c + 3]);
        unsigned wA1 = pk2(p[8 * c + 4], p[8 * c + 5]);
        unsigned wB1 = pk2(p[8 * c + 6], p[8 * c + 7]);
        pswap(wA0, wA1);
        pswap(wB0, wB1);
        u32x4 pw;
        pw[0] = wA0; pw[1] = wB0; pw[2] = wA1; pw[3] = wB1;
        bf16x8 pb = __builtin_bit_cast(bf16x8, pw);
        int kc = 2 * t2 + c;
        o0 = __builtin_amdgcn_mfma_f32_32x32x16_bf16(vf[kc], pb, o0, 0, 0, 0);
        o1 = __builtin_amdgcn_mfma_f32_32x32x16_bf16(vf[4 + kc], pb, o1, 0, 0, 0);
      }
    }

    // ---- drain adj(it+1) regs (had K/V issue + full compute to arrive),
    // write them into buf[cur^1] (WAR-safe: its readers passed the PREVIOUS
    // barrier), publish via lgkmcnt(0) + barrier.
    asm volatile("s_waitcnt vmcnt(0)" ::: "memory");
    SCHED0();
#pragma unroll
    for (int i = 0; i < 8; ++i) {
      int row = 8 * w + i;
      *reinterpret_cast<f32x4*>(&smem[cur ^ 1][row][l << 2]) = areg[i];
    }
    asm volatile("s_waitcnt lgkmcnt(0)" ::: "memory");
    SCHED0();
    __builtin_amdgcn_s_barrier();
    SCHED0();
  }

  __syncthreads();

  // ---- epilogue: reuse smem for cross-wave combine
  float stot = sacc + __shfl_xor(sacc, 32);
  float* opart = &smem[0][0][0];        // [4][64][32]
  float* ssum = &smem[0][0][0] + 8192;  // [4][32]
  if (l < 32) ssum[w * 32 + l31] = stot;
#pragma unroll
  for (int r = 0; r < 16; ++r) {
    int d = (r & 3) + 8 * (r >> 2) + 4 * lh;
    opart[w * 2048 + d * 32 + l31] = o0[r];
    opart[w * 2048 + (32 + d) * 32 + l31] = o1[r];
  }
  __syncthreads();

#pragma unroll
  for (int k = 0; k < 8; ++k) {
    int idx = k * 256 + tid;
    int q = idx & 31, d = idx >> 5;
    float s = ssum[q] + ssum[32 + q] + ssum[64 + q] + ssum[96 + q];
    float ov = opart[d * 32 + q] + opart[2048 + d * 32 + q] +
               opart[4096 + d * 32 + q] + opart[6144 + d * 32 + q];
    out[(size_t)(hh * NN + q0 + q) * DOUT + d] = ov / s;
  }
}

extern "C" void kernel_launch(void* const* d_in, const int* in_sizes, int n_in,
                              void* d_out, int out_size, void* d_ws, size_t ws_size,
                              hipStream_t stream) {
  const float* adj = (const float*)d_in[0];
  const float* h   = (const float*)d_in[1];
  const float* WQ  = (const float*)d_in[2];
  const float* bQ  = (const float*)d_in[3];
  const float* WK  = (const float*)d_in[4];
  const float* bK  = (const float*)d_in[5];
  const float* WV  = (const float*)d_in[6];
  const float* bV  = (const float*)d_in[7];
  float* out = (float*)d_out;

  if (ws_size < 12976128) return;  // need ~12.4 MB scratch

  char* ws = (char*)d_ws;
  bf16_t* hb = (bf16_t*)ws;                 // [N][256] bf16            3,145,728 B
  bf16_t* Wt = (bf16_t*)(ws + 3145728);     // [3][H][64][256] bf16       393,216 B
  bf16_t* Qb = (bf16_t*)(ws + 3538944);     // [H][N][64] bf16 (scaled) 3,145,728 B
  bf16_t* Kf = (bf16_t*)(ws + 6684672);     // [H] K fragments          3,145,728 B
  bf16_t* Vf = (bf16_t*)(ws + 9830400);     // [H] V fragments          3,145,728 B

  prep_kernel<<<1024, 256, 0, stream>>>(h, WQ, WK, WV, hb, Wt);
  proj_kernel<<<dim3(96, 4), 256, 0, stream>>>(hb, Wt, bQ, bK, bV, Qb, Kf, Vf);
  attn_kernel<<<768, 256, 0, stream>>>(adj, Qb, Kf, Vf, out);
}

// Round 12
// 167.817 us; speedup vs baseline: 1.3004x; 1.0485x over previous
//
#include <hip/hip_runtime.h>
#include <hip/hip_bf16.h>

#define NN 6144
#define HEADS 4
#define DIN 256
#define DOUT 64

typedef __bf16 bf16_t;
typedef bf16_t bf16x8 __attribute__((ext_vector_type(8)));
typedef float f32x16 __attribute__((ext_vector_type(16)));
typedef float f32x4 __attribute__((ext_vector_type(4)));
typedef unsigned u32x4 __attribute__((ext_vector_type(4)));

#if __has_builtin(__builtin_amdgcn_exp2f)
#define EXP2(x) __builtin_amdgcn_exp2f(x)
#else
#define EXP2(x) exp2f(x)
#endif

static __device__ __forceinline__ f32x16 zero16() {
  f32x16 z;
#pragma unroll
  for (int i = 0; i < 16; ++i) z[i] = 0.0f;
  return z;
}

static __device__ __forceinline__ bf16x8 ldg8(const bf16_t* p) {
  return *reinterpret_cast<const bf16x8*>(p);
}

// pack two f32 -> one u32 of 2 bf16 (element 0 in low half)
static __device__ __forceinline__ unsigned pk2(float a, float b) {
  union { bf16_t h[2]; unsigned u; } z;
  z.h[0] = (bf16_t)a;
  z.h[1] = (bf16_t)b;
  return z.u;
}

// v_permlane32_swap_b32: x.hi32lanes <-> y.lo32lanes
static __device__ __forceinline__ void pswap(unsigned& x, unsigned& y) {
  asm("v_permlane32_swap_b32 %0, %1" : "+v"(x), "+v"(y));
}

// non-temporal 16B read (read-once adj stream; don't evict K/V from L2)
static __device__ __forceinline__ f32x4 ldnt4(const float* p) {
  return __builtin_nontemporal_load(reinterpret_cast<const f32x4*>(p));
}

#define SCHED0() __builtin_amdgcn_sched_barrier(0)

// ---------------- prep: h -> bf16, W -> transposed bf16 (scale folded into WQ)
__global__ __launch_bounds__(256) void prep_kernel(
    const float* __restrict__ h, const float* __restrict__ WQ,
    const float* __restrict__ WK, const float* __restrict__ WV,
    bf16_t* __restrict__ hb, bf16_t* __restrict__ Wt) {
  int stride = gridDim.x * blockDim.x;
  int idx = blockIdx.x * blockDim.x + threadIdx.x;
  for (int i = idx; i < NN * DIN; i += stride)
    hb[i] = (bf16_t)h[i];
  const float c2 = 0.0625f * 1.4426950408889634f;  // (1/sqrt(256)) * log2(e)
  for (int i = idx; i < 3 * HEADS * DOUT * DIN; i += stride) {
    int d = i & (DIN - 1);
    int o = (i >> 8) & (DOUT - 1);
    int hh = (i >> 14) & (HEADS - 1);
    int m = i >> 16;
    const float* W = (m == 0) ? WQ : (m == 1) ? WK : WV;
    float v = W[(hh * DIN + d) * DOUT + o];
    if (m == 0) v *= c2;
    Wt[i] = (bf16_t)v;  // Wt[m][hh][o][d]
  }
}

// ---------------- proj: Qb row-major [H][N][64]; Kf/Vf in MFMA-fragment order.
__global__ __launch_bounds__(256) void proj_kernel(
    const bf16_t* __restrict__ hb, const bf16_t* __restrict__ Wt,
    const float* __restrict__ bQ, const float* __restrict__ bK,
    const float* __restrict__ bV,
    bf16_t* __restrict__ Qb, bf16_t* __restrict__ Kf, bf16_t* __restrict__ Vf) {
  const float c2 = 0.0625f * 1.4426950408889634f;
  int tid = threadIdx.x;
  int w = tid >> 6, l = tid & 63;
  int l31 = l & 31, lh = l >> 5;
  int hh = blockIdx.y;
  int n0 = blockIdx.x * 64;

#pragma unroll
  for (int s = 0; s < 3; ++s) {
    int t = w * 3 + s;  // 12 tiles: 0-3 Q, 4-7 K, 8-11 V
    if (t < 8) {
      int m = t >> 2;            // 0=Q, 1=K
      int rh = (t >> 1) & 1;     // row half (key half)
      int oh = t & 1;            // out-col half
      const bf16_t* arow = hb + (n0 + rh * 32 + l31) * DIN + 8 * lh;
      const bf16_t* brow = Wt + ((m * HEADS + hh) * DOUT + oh * 32 + l31) * DIN + 8 * lh;
      f32x16 acc = zero16();
#pragma unroll
      for (int kc = 0; kc < 16; ++kc)
        acc = __builtin_amdgcn_mfma_f32_32x32x16_bf16(ldg8(arow + kc * 16),
                                                      ldg8(brow + kc * 16), acc, 0, 0, 0);
      const float* bias = (m == 0) ? bQ : bK;
      float bv = bias[hh * DOUT + oh * 32 + l31];
      if (m == 0) {
        bv *= c2;
        bf16_t* outp = Qb + (size_t)(hh * NN + n0 + rh * 32) * DOUT + oh * 32 + l31;
#pragma unroll
        for (int r = 0; r < 16; ++r) {
          int q = (r & 3) + 8 * (r >> 2) + 4 * lh;
          outp[q * DOUT] = (bf16_t)(acc[r] + bv);
        }
      } else {
        int o = oh * 32 + l31;
        bf16_t* outp = Kf + (size_t)hh * 393216 + (n0 >> 6) * 4096 + rh * 2048 +
                       (o >> 4) * 512 + ((o >> 3) & 1) * 256 + (o & 7);
#pragma unroll
        for (int r = 0; r < 16; ++r) {
          int rr = (r & 3) + 8 * (r >> 2) + 4 * lh;  // key & 31
          outp[rr * 8] = (bf16_t)(acc[r] + bv);
        }
      }
    } else {
      int tt = t - 8;
      int oh = tt >> 1, nh = tt & 1;  // oh = d half, nh = key half
      const bf16_t* arow = Wt + ((2 * HEADS + hh) * DOUT + oh * 32 + l31) * DIN + 8 * lh;
      const bf16_t* brow = hb + (n0 + nh * 32 + l31) * DIN + 8 * lh;
      f32x16 acc = zero16();
#pragma unroll
      for (int kc = 0; kc < 16; ++kc)
        acc = __builtin_amdgcn_mfma_f32_32x32x16_bf16(ldg8(arow + kc * 16),
                                                      ldg8(brow + kc * 16), acc, 0, 0, 0);
      int k6 = nh * 32 + l31;
      bf16_t* outp = Vf + (size_t)hh * 393216 + (n0 >> 6) * 4096 + oh * 2048 +
                     (k6 >> 4) * 512 + ((k6 >> 3) & 1) * 256 + (k6 & 7);
#pragma unroll
      for (int r = 0; r < 16; ++r) {
        int rr = (r & 3) + 8 * (r >> 2) + 4 * lh;  // d & 31
        float bvv = bV[hh * DOUT + oh * 32 + rr];
        outp[rr * 8] = (bf16_t)(acc[r] + bvv);
      }
    }
  }
}

// ---------------- attention: r11 structure + per-block COLUMN-PHASE ROTATION.
// All prior variants swept adj columns 0->23 in lockstep; with the 24-KB row
// stride aliasing to few HBM channels per column phase, the whole chip camped
// on a channel subset. Rotating each block's start tile (t0 = bid % 24)
// spreads concurrent accesses over all column phases -> all channels.
__global__ __launch_bounds__(256, 2) void attn_kernel(
    const float* __restrict__ adj, const bf16_t* __restrict__ Qb,
    const bf16_t* __restrict__ Kf, const bf16_t* __restrict__ Vf,
    float* __restrict__ out) {
  __shared__ __align__(16) float smem[2][32][256];  // 64 KB; reused for epilogue

  int tid = threadIdx.x;
  int w = tid >> 6, l = tid & 63;
  int l31 = l & 31, lh = l >> 5;

  // bijective XCD swizzle (768 % 8 == 0): XCD k owns work-ids k*96..k*96+95 =
  // half of one head -> K/V working set 1.5 MB, L2-resident per XCD.
  int bid = blockIdx.x;
  int work = (bid & 7) * 96 + (bid >> 3);
  int hh = work / 192;
  int q0 = (work % 192) * 32;
  int t0 = bid % 24;  // column-phase rotation (768/24 = 32 blocks per phase)

  // Q as B-fragment: col = q = l31, k = kc*16 + 8*lh + 0..7  (pre-scaled by c2)
  const bf16_t* Qrow = Qb + (size_t)(hh * NN + q0 + l31) * DOUT + 8 * lh;
  bf16x8 qf[4];
#pragma unroll
  for (int kc = 0; kc < 4; ++kc) qf[kc] = ldg8(Qrow + kc * 16);

  const bf16_t* Kh = Kf + (size_t)hh * 393216;
  const bf16_t* Vh = Vf + (size_t)hh * 393216;
  const float* adjq = adj + (size_t)hh * NN * NN + (size_t)q0 * NN;

  f32x16 o0 = zero16(), o1 = zero16();
  float sacc = 0.0f;

  f32x4 areg[8];  // in-flight adj tile (wave w owns rows 8w..8w+7)

  // ---- prologue: tile t0 -> regs -> LDS buf 0 (swizzle applied on ds_write:
  // LDS[row][u] = G[row][u ^ (row&7)], matching the readback XOR)
#pragma unroll
  for (int i = 0; i < 8; ++i) {
    int row = 8 * w + i;
    areg[i] = ldnt4(adjq + (size_t)row * NN + t0 * 256 + ((l ^ i) << 2));
  }
  asm volatile("s_waitcnt vmcnt(0)" ::: "memory");
  SCHED0();
#pragma unroll
  for (int i = 0; i < 8; ++i) {
    int row = 8 * w + i;
    *reinterpret_cast<f32x4*>(&smem[0][row][l << 2]) = areg[i];
  }
  asm volatile("s_waitcnt lgkmcnt(0)" ::: "memory");
  SCHED0();
  __builtin_amdgcn_s_barrier();
  SCHED0();

  for (int it = 0; it < 24; ++it) {
    int cur = it & 1;
    // rotated tile indices: this iter consumes tile tc; prefetch tile tn
    int tc = t0 + it;
    if (tc >= 24) tc -= 24;
    int tn = tc + 1;
    if (tn >= 24) tn -= 24;
    if (it == 23) tn = tc;  // dummy re-stage keeps vmcnt counts uniform
    int chunk = tc * 4 + w;  // this wave's 64-key chunk

    // ---- K/V fragments first (16 VMEM)
    const bf16_t* kbase = Kh + (size_t)chunk * 4096 + l * 8;
    const bf16_t* vbase = Vh + (size_t)chunk * 4096 + l * 8;
    bf16x8 kf[8], vf[8];
#pragma unroll
    for (int x = 0; x < 4; ++x) {
      kf[x] = ldg8(kbase + x * 512);
      kf[4 + x] = ldg8(kbase + 2048 + x * 512);
    }
#pragma unroll
    for (int x = 0; x < 4; ++x) {
      vf[x] = ldg8(vbase + x * 512);
      vf[4 + x] = ldg8(vbase + 2048 + x * 512);
    }
    SCHED0();

    // ---- issue adj tile tn into registers (8 VMEM, newest; the compiler's
    // K/V waits (vmcnt>=8) never drain these). Pre-swizzled source so the
    // later linear ds_write yields LDS[row][u] = G[row][u^(row&7)].
#pragma unroll
    for (int i = 0; i < 8; ++i) {
      int row = 8 * w + i;
      areg[i] = ldnt4(adjq + (size_t)row * NN + tn * 256 + ((l ^ i) << 2));
    }
    SCHED0();

    // ---- adj readback: row = own q (l31), swizzled chunk
    f32x4 av[8];
#pragma unroll
    for (int t2 = 0; t2 < 2; ++t2)
#pragma unroll
      for (int g = 0; g < 4; ++g) {
        int c = 16 * w + 8 * t2 + 2 * g + lh;
        av[t2 * 4 + g] =
            *reinterpret_cast<const f32x4*>(&smem[cur][l31][(c ^ (l31 & 7)) << 2]);
      }

    // ---- S^T = K · Q^T : row = key (reg), col = q (lane)
    f32x16 s0 = zero16(), s1 = zero16();
#pragma unroll
    for (int kc = 0; kc < 4; ++kc) {
      s0 = __builtin_amdgcn_mfma_f32_32x32x16_bf16(kf[kc], qf[kc], s0, 0, 0, 0);
      s1 = __builtin_amdgcn_mfma_f32_32x32x16_bf16(kf[4 + kc], qf[kc], s1, 0, 0, 0);
    }

    // ---- P = exp2(S^T * adj); pack + permlane32_swap into PV B-frags; PV MFMA
#pragma unroll
    for (int t2 = 0; t2 < 2; ++t2) {
      f32x16 st = t2 ? s1 : s0;
      float p[16];
#pragma unroll
      for (int r = 0; r < 16; ++r) {
        float pv = EXP2(st[r] * av[4 * t2 + (r >> 2)][r & 3]);
        p[r] = pv;
        sacc += pv;
      }
#pragma unroll
      for (int c = 0; c < 2; ++c) {
        unsigned wA0 = pk2(p[8 * c + 0], p[8 * c + 1]);
        unsigned wB0 = pk2(p[8 * c + 2], p[8 * c + 3]);
        unsigned wA1 = pk2(p[8 * c + 4], p[8 * c + 5]);
        unsigned wB1 = pk2(p[8 * c + 6], p[8 * c + 7]);
        pswap(wA0, wA1);
        pswap(wB0, wB1);
        u32x4 pw;
        pw[0] = wA0; pw[1] = wB0; pw[2] = wA1; pw[3] = wB1;
        bf16x8 pb = __builtin_bit_cast(bf16x8, pw);
        int kc = 2 * t2 + c;
        o0 = __builtin_amdgcn_mfma_f32_32x32x16_bf16(vf[kc], pb, o0, 0, 0, 0);
        o1 = __builtin_amdgcn_mfma_f32_32x32x16_bf16(vf[4 + kc], pb, o1, 0, 0, 0);
      }
    }

    // ---- drain adj(tn) regs (had K/V issue + full compute to arrive),
    // write them into buf[cur^1] (WAR-safe: its readers passed the PREVIOUS
    // barrier), publish via lgkmcnt(0) + barrier.
    asm volatile("s_waitcnt vmcnt(0)" ::: "memory");
    SCHED0();
#pragma unroll
    for (int i = 0; i < 8; ++i) {
      int row = 8 * w + i;
      *reinterpret_cast<f32x4*>(&smem[cur ^ 1][row][l << 2]) = areg[i];
    }
    asm volatile("s_waitcnt lgkmcnt(0)" ::: "memory");
    SCHED0();
    __builtin_amdgcn_s_barrier();
    SCHED0();
  }

  __syncthreads();

  // ---- epilogue: reuse smem for cross-wave combine
  float stot = sacc + __shfl_xor(sacc, 32);
  float* opart = &smem[0][0][0];        // [4][64][32]
  float* ssum = &smem[0][0][0] + 8192;  // [4][32]
  if (l < 32) ssum[w * 32 + l31] = stot;
#pragma unroll
  for (int r = 0; r < 16; ++r) {
    int d = (r & 3) + 8 * (r >> 2) + 4 * lh;
    opart[w * 2048 + d * 32 + l31] = o0[r];
    opart[w * 2048 + (32 + d) * 32 + l31] = o1[r];
  }
  __syncthreads();

#pragma unroll
  for (int k = 0; k < 8; ++k) {
    int idx = k * 256 + tid;
    int q = idx & 31, d = idx >> 5;
    float s = ssum[q] + ssum[32 + q] + ssum[64 + q] + ssum[96 + q];
    float ov = opart[d * 32 + q] + opart[2048 + d * 32 + q] +
               opart[4096 + d * 32 + q] + opart[6144 + d * 32 + q];
    out[(size_t)(hh * NN + q0 + q) * DOUT + d] = ov / s;
  }
}

extern "C" void kernel_launch(void* const* d_in, const int* in_sizes, int n_in,
                              void* d_out, int out_size, void* d_ws, size_t ws_size,
                              hipStream_t stream) {
  const float* adj = (const float*)d_in[0];
  const float* h   = (const float*)d_in[1];
  const float* WQ  = (const float*)d_in[2];
  const float* bQ  = (const float*)d_in[3];
  const float* WK  = (const float*)d_in[4];
  const float* bK  = (const float*)d_in[5];
  const float* WV  = (const float*)d_in[6];
  const float* bV  = (const float*)d_in[7];
  float* out = (float*)d_out;

  if (ws_size < 12976128) return;  // need ~12.4 MB scratch

  char* ws = (char*)d_ws;
  bf16_t* hb = (bf16_t*)ws;                 // [N][256] bf16            3,145,728 B
  bf16_t* Wt = (bf16_t*)(ws + 3145728);     // [3][H][64][256] bf16       393,216 B
  bf16_t* Qb = (bf16_t*)(ws + 3538944);     // [H][N][64] bf16 (scaled) 3,145,728 B
  bf16_t* Kf = (bf16_t*)(ws + 6684672);     // [H] K fragments          3,145,728 B
  bf16_t* Vf = (bf16_t*)(ws + 9830400);     // [H] V fragments          3,145,728 B

  prep_kernel<<<1024, 256, 0, stream>>>(h, WQ, WK, WV, hb, Wt);
  proj_kernel<<<dim3(96, 4), 256, 0, stream>>>(hb, Wt, bQ, bK, bV, Qb, Kf, Vf);
  attn_kernel<<<768, 256, 0, stream>>>(adj, Qb, Kf, Vf, out);
}

// Round 13
// 160.882 us; speedup vs baseline: 1.3565x; 1.0431x over previous
//
#include <hip/hip_runtime.h>
#include <hip/hip_bf16.h>

#define NN 6144
#define HEADS 4
#define DIN 256
#define DOUT 64

typedef __bf16 bf16_t;
typedef bf16_t bf16x8 __attribute__((ext_vector_type(8)));
typedef float f32x16 __attribute__((ext_vector_type(16)));
typedef float f32x4 __attribute__((ext_vector_type(4)));
typedef unsigned u32x4 __attribute__((ext_vector_type(4)));

#if __has_builtin(__builtin_amdgcn_exp2f)
#define EXP2(x) __builtin_amdgcn_exp2f(x)
#else
#define EXP2(x) exp2f(x)
#endif

static __device__ __forceinline__ f32x16 zero16() {
  f32x16 z;
#pragma unroll
  for (int i = 0; i < 16; ++i) z[i] = 0.0f;
  return z;
}

static __device__ __forceinline__ bf16x8 ldg8(const bf16_t* p) {
  return *reinterpret_cast<const bf16x8*>(p);
}

// pack two f32 -> one u32 of 2 bf16 (element 0 in low half)
static __device__ __forceinline__ unsigned pk2(float a, float b) {
  union { bf16_t h[2]; unsigned u; } z;
  z.h[0] = (bf16_t)a;
  z.h[1] = (bf16_t)b;
  return z.u;
}

// v_permlane32_swap_b32: x.hi32lanes <-> y.lo32lanes
static __device__ __forceinline__ void pswap(unsigned& x, unsigned& y) {
  asm("v_permlane32_swap_b32 %0, %1" : "+v"(x), "+v"(y));
}

// non-temporal 16B read (read-once adj stream; don't evict K/V from L2)
static __device__ __forceinline__ f32x4 ldnt4(const float* p) {
  return __builtin_nontemporal_load(reinterpret_cast<const f32x4*>(p));
}

#define SCHED0() __builtin_amdgcn_sched_barrier(0)
#define VW(N)                                                   \
  asm volatile("s_waitcnt vmcnt(" #N ")" ::: "memory");         \
  SCHED0();

// ---------------- prep: h -> bf16, W -> transposed bf16 (scale folded into WQ)
__global__ __launch_bounds__(256) void prep_kernel(
    const float* __restrict__ h, const float* __restrict__ WQ,
    const float* __restrict__ WK, const float* __restrict__ WV,
    bf16_t* __restrict__ hb, bf16_t* __restrict__ Wt) {
  int stride = gridDim.x * blockDim.x;
  int idx = blockIdx.x * blockDim.x + threadIdx.x;
  for (int i = idx; i < NN * DIN; i += stride)
    hb[i] = (bf16_t)h[i];
  const float c2 = 0.0625f * 1.4426950408889634f;  // (1/sqrt(256)) * log2(e)
  for (int i = idx; i < 3 * HEADS * DOUT * DIN; i += stride) {
    int d = i & (DIN - 1);
    int o = (i >> 8) & (DOUT - 1);
    int hh = (i >> 14) & (HEADS - 1);
    int m = i >> 16;
    const float* W = (m == 0) ? WQ : (m == 1) ? WK : WV;
    float v = W[(hh * DIN + d) * DOUT + o];
    if (m == 0) v *= c2;
    Wt[i] = (bf16_t)v;  // Wt[m][hh][o][d]
  }
}

// ---------------- proj: Qb row-major [H][N][64]; Kf/Vf in MFMA-fragment order.
__global__ __launch_bounds__(256) void proj_kernel(
    const bf16_t* __restrict__ hb, const bf16_t* __restrict__ Wt,
    const float* __restrict__ bQ, const float* __restrict__ bK,
    const float* __restrict__ bV,
    bf16_t* __restrict__ Qb, bf16_t* __restrict__ Kf, bf16_t* __restrict__ Vf) {
  const float c2 = 0.0625f * 1.4426950408889634f;
  int tid = threadIdx.x;
  int w = tid >> 6, l = tid & 63;
  int l31 = l & 31, lh = l >> 5;
  int hh = blockIdx.y;
  int n0 = blockIdx.x * 64;

#pragma unroll
  for (int s = 0; s < 3; ++s) {
    int t = w * 3 + s;  // 12 tiles: 0-3 Q, 4-7 K, 8-11 V
    if (t < 8) {
      int m = t >> 2;            // 0=Q, 1=K
      int rh = (t >> 1) & 1;     // row half (key half)
      int oh = t & 1;            // out-col half
      const bf16_t* arow = hb + (n0 + rh * 32 + l31) * DIN + 8 * lh;
      const bf16_t* brow = Wt + ((m * HEADS + hh) * DOUT + oh * 32 + l31) * DIN + 8 * lh;
      f32x16 acc = zero16();
#pragma unroll
      for (int kc = 0; kc < 16; ++kc)
        acc = __builtin_amdgcn_mfma_f32_32x32x16_bf16(ldg8(arow + kc * 16),
                                                      ldg8(brow + kc * 16), acc, 0, 0, 0);
      const float* bias = (m == 0) ? bQ : bK;
      float bv = bias[hh * DOUT + oh * 32 + l31];
      if (m == 0) {
        bv *= c2;
        bf16_t* outp = Qb + (size_t)(hh * NN + n0 + rh * 32) * DOUT + oh * 32 + l31;
#pragma unroll
        for (int r = 0; r < 16; ++r) {
          int q = (r & 3) + 8 * (r >> 2) + 4 * lh;
          outp[q * DOUT] = (bf16_t)(acc[r] + bv);
        }
      } else {
        int o = oh * 32 + l31;
        bf16_t* outp = Kf + (size_t)hh * 393216 + (n0 >> 6) * 4096 + rh * 2048 +
                       (o >> 4) * 512 + ((o >> 3) & 1) * 256 + (o & 7);
#pragma unroll
        for (int r = 0; r < 16; ++r) {
          int rr = (r & 3) + 8 * (r >> 2) + 4 * lh;  // key & 31
          outp[rr * 8] = (bf16_t)(acc[r] + bv);
        }
      }
    } else {
      int tt = t - 8;
      int oh = tt >> 1, nh = tt & 1;  // oh = d half, nh = key half
      const bf16_t* arow = Wt + ((2 * HEADS + hh) * DOUT + oh * 32 + l31) * DIN + 8 * lh;
      const bf16_t* brow = hb + (n0 + nh * 32 + l31) * DIN + 8 * lh;
      f32x16 acc = zero16();
#pragma unroll
      for (int kc = 0; kc < 16; ++kc)
        acc = __builtin_amdgcn_mfma_f32_32x32x16_bf16(ldg8(arow + kc * 16),
                                                      ldg8(brow + kc * 16), acc, 0, 0, 0);
      int k6 = nh * 32 + l31;
      bf16_t* outp = Vf + (size_t)hh * 393216 + (n0 >> 6) * 4096 + oh * 2048 +
                     (k6 >> 4) * 512 + ((k6 >> 3) & 1) * 256 + (k6 & 7);
#pragma unroll
      for (int r = 0; r < 16; ++r) {
        int rr = (r & 3) + 8 * (r >> 2) + 4 * lh;  // d & 31
        float bvv = bV[hh * DOUT + oh * 32 + rr];
        outp[rr * 8] = (bf16_t)(acc[r] + bvv);
      }
    }
  }
}

// one iteration body. AIN = reg set holding tile IT+1 (in flight since last
// body; drained + ds_written at the end). AOUT = reg set receiving tile IT+2.
// CUR = LDS buffer parity (compile-time: bodies alternate 0/1).
// vmcnt ledger: at entry IN(8,oldest); +KV(16); +OUT(8). Compiler's kf wait
// = vmcnt(16) (drains IN, ~1.8 iterations old -> no stall); vf wait =
// vmcnt(8); explicit VW(8) before the IN ds_write.
#define ATTN_BODY(AIN, AOUT, IT, CUR)                                          \
  {                                                                            \
    int tc = t0 + (IT);                                                        \
    if (tc >= 24) tc -= 24;                                                    \
    int tni = t0 + (IT) + 2;                                                   \
    if (tni >= 24) tni -= 24;                                                  \
    int chunk = tc * 4 + w;                                                    \
    const bf16_t* kbase = Kh + (size_t)chunk * 4096 + l * 8;                   \
    const bf16_t* vbase = Vh + (size_t)chunk * 4096 + l * 8;                   \
    bf16x8 kf[8], vf[8];                                                       \
    _Pragma("unroll") for (int x = 0; x < 4; ++x) {                            \
      kf[x] = ldg8(kbase + x * 512);                                           \
      kf[4 + x] = ldg8(kbase + 2048 + x * 512);                                \
    }                                                                          \
    _Pragma("unroll") for (int x = 0; x < 4; ++x) {                            \
      vf[x] = ldg8(vbase + x * 512);                                           \
      vf[4 + x] = ldg8(vbase + 2048 + x * 512);                                \
    }                                                                          \
    SCHED0();                                                                  \
    if ((IT) < 22) { /* issue tile IT+2 (skip dummies: saves 48 MB HBM) */     \
      _Pragma("unroll") for (int i = 0; i < 8; ++i) {                          \
        int row = 8 * w + i;                                                   \
        AOUT[i] = ldnt4(adjq + (size_t)row * NN + tni * 256 + ((l ^ i) << 2)); \
      }                                                                        \
    }                                                                          \
    SCHED0();                                                                  \
    f32x4 av[8];                                                               \
    _Pragma("unroll") for (int t2 = 0; t2 < 2; ++t2)                           \
        _Pragma("unroll") for (int g = 0; g < 4; ++g) {                        \
      int c = 16 * w + 8 * t2 + 2 * g + lh;                                    \
      av[t2 * 4 + g] = *reinterpret_cast<const f32x4*>(                        \
          &smem[CUR][l31][(c ^ (l31 & 7)) << 2]);                              \
    }                                                                          \
    f32x16 s0 = zero16(), s1 = zero16();                                       \
    _Pragma("unroll") for (int kc = 0; kc < 4; ++kc) {                         \
      s0 = __builtin_amdgcn_mfma_f32_32x32x16_bf16(kf[kc], qf[kc], s0, 0, 0, 0);\
      s1 = __builtin_amdgcn_mfma_f32_32x32x16_bf16(kf[4 + kc], qf[kc], s1, 0, 0, 0);\
    }                                                                          \
    _Pragma("unroll") for (int t2 = 0; t2 < 2; ++t2) {                         \
      f32x16 st = t2 ? s1 : s0;                                                \
      float p[16];                                                             \
      _Pragma("unroll") for (int r = 0; r < 16; ++r) {                         \
        float pv = EXP2(st[r] * av[4 * t2 + (r >> 2)][r & 3]);                 \
        p[r] = pv;                                                             \
        sacc += pv;                                                            \
      }                                                                        \
      _Pragma("unroll") for (int c2 = 0; c2 < 2; ++c2) {                       \
        unsigned wA0 = pk2(p[8 * c2 + 0], p[8 * c2 + 1]);                      \
        unsigned wB0 = pk2(p[8 * c2 + 2], p[8 * c2 + 3]);                      \
        unsigned wA1 = pk2(p[8 * c2 + 4], p[8 * c2 + 5]);                      \
        unsigned wB1 = pk2(p[8 * c2 + 6], p[8 * c2 + 7]);                      \
        pswap(wA0, wA1);                                                       \
        pswap(wB0, wB1);                                                       \
        u32x4 pw;                                                              \
        pw[0] = wA0; pw[1] = wB0; pw[2] = wA1; pw[3] = wB1;                    \
        bf16x8 pb = __builtin_bit_cast(bf16x8, pw);                            \
        int kc = 2 * t2 + c2;                                                  \
        o0 = __builtin_amdgcn_mfma_f32_32x32x16_bf16(vf[kc], pb, o0, 0, 0, 0); \
        o1 = __builtin_amdgcn_mfma_f32_32x32x16_bf16(vf[4 + kc], pb, o1, 0, 0, 0);\
      }                                                                        \
    }                                                                          \
    if ((IT) < 23) { /* drain IN (tile IT+1), publish to buf[CUR^1] */         \
      VW(8)                                                                    \
      _Pragma("unroll") for (int i = 0; i < 8; ++i) {                          \
        int row = 8 * w + i;                                                   \
        *reinterpret_cast<f32x4*>(&smem[(CUR) ^ 1][row][l << 2]) = AIN[i];     \
      }                                                                        \
      asm volatile("s_waitcnt lgkmcnt(0)" ::: "memory");                       \
      SCHED0();                                                                \
      __builtin_amdgcn_s_barrier();                                           \
      SCHED0();                                                                \
    }                                                                          \
  }

// ---------------- attention: r12 structure + DEPTH-2 adj register pipeline.
// Two reg tile-buffers keep ~2 iterations of the adj stream in flight at all
// times (doubled in-flight duty -> Little's-law BW).
__global__ __launch_bounds__(256, 2) void attn_kernel(
    const float* __restrict__ adj, const bf16_t* __restrict__ Qb,
    const bf16_t* __restrict__ Kf, const bf16_t* __restrict__ Vf,
    float* __restrict__ out) {
  __shared__ __align__(16) float smem[2][32][256];  // 64 KB; reused for epilogue

  int tid = threadIdx.x;
  int w = tid >> 6, l = tid & 63;
  int l31 = l & 31, lh = l >> 5;

  // bijective XCD swizzle (768 % 8 == 0): XCD k owns work-ids k*96..k*96+95 =
  // half of one head -> K/V working set 1.5 MB, L2-resident per XCD.
  int bid = blockIdx.x;
  int work = (bid & 7) * 96 + (bid >> 3);
  int hh = work / 192;
  int q0 = (work % 192) * 32;
  int t0 = bid % 24;  // column-phase rotation (768/24 = 32 blocks per phase)

  // Q as B-fragment: col = q = l31, k = kc*16 + 8*lh + 0..7  (pre-scaled by c2)
  const bf16_t* Qrow = Qb + (size_t)(hh * NN + q0 + l31) * DOUT + 8 * lh;
  bf16x8 qf[4];
#pragma unroll
  for (int kc = 0; kc < 4; ++kc) qf[kc] = ldg8(Qrow + kc * 16);

  const bf16_t* Kh = Kf + (size_t)hh * 393216;
  const bf16_t* Vh = Vf + (size_t)hh * 393216;
  const float* adjq = adj + (size_t)hh * NN * NN + (size_t)q0 * NN;

  f32x16 o0 = zero16(), o1 = zero16();
  float sacc = 0.0f;

  f32x4 aregA[8], aregB[8];

  // ---- prologue: issue tiles t0 -> A and t0+1 -> B; drain A only; write A
  // to LDS buf0 (swizzle on write: LDS[row][u] = G[row][u^(row&7)]).
#pragma unroll
  for (int i = 0; i < 8; ++i) {
    int row = 8 * w + i;
    aregA[i] = ldnt4(adjq + (size_t)row * NN + t0 * 256 + ((l ^ i) << 2));
  }
  int t1 = t0 + 1;
  if (t1 >= 24) t1 -= 24;
#pragma unroll
  for (int i = 0; i < 8; ++i) {
    int row = 8 * w + i;
    aregB[i] = ldnt4(adjq + (size_t)row * NN + t1 * 256 + ((l ^ i) << 2));
  }
  VW(8)  // aregA landed (8 newer = aregB still in flight)
#pragma unroll
  for (int i = 0; i < 8; ++i) {
    int row = 8 * w + i;
    *reinterpret_cast<f32x4*>(&smem[0][row][l << 2]) = aregA[i];
  }
  asm volatile("s_waitcnt lgkmcnt(0)" ::: "memory");
  SCHED0();
  __builtin_amdgcn_s_barrier();
  SCHED0();

  for (int it2 = 0; it2 < 12; ++it2) {
    ATTN_BODY(aregB, aregA, 2 * it2, 0)
    ATTN_BODY(aregA, aregB, 2 * it2 + 1, 1)
  }

  VW(0)
  __syncthreads();

  // ---- epilogue: reuse smem for cross-wave combine
  float stot = sacc + __shfl_xor(sacc, 32);
  float* opart = &smem[0][0][0];        // [4][64][32]
  float* ssum = &smem[0][0][0] + 8192;  // [4][32]
  if (l < 32) ssum[w * 32 + l31] = stot;
#pragma unroll
  for (int r = 0; r < 16; ++r) {
    int d = (r & 3) + 8 * (r >> 2) + 4 * lh;
    opart[w * 2048 + d * 32 + l31] = o0[r];
    opart[w * 2048 + (32 + d) * 32 + l31] = o1[r];
  }
  __syncthreads();

#pragma unroll
  for (int k = 0; k < 8; ++k) {
    int idx = k * 256 + tid;
    int q = idx & 31, d = idx >> 5;
    float s = ssum[q] + ssum[32 + q] + ssum[64 + q] + ssum[96 + q];
    float ov = opart[d * 32 + q] + opart[2048 + d * 32 + q] +
               opart[4096 + d * 32 + q] + opart[6144 + d * 32 + q];
    out[(size_t)(hh * NN + q0 + q) * DOUT + d] = ov / s;
  }
}

extern "C" void kernel_launch(void* const* d_in, const int* in_sizes, int n_in,
                              void* d_out, int out_size, void* d_ws, size_t ws_size,
                              hipStream_t stream) {
  const float* adj = (const float*)d_in[0];
  const float* h   = (const float*)d_in[1];
  const float* WQ  = (const float*)d_in[2];
  const float* bQ  = (const float*)d_in[3];
  const float* WK  = (const float*)d_in[4];
  const float* bK  = (const float*)d_in[5];
  const float* WV  = (const float*)d_in[6];
  const float* bV  = (const float*)d_in[7];
  float* out = (float*)d_out;

  if (ws_size < 12976128) return;  // need ~12.4 MB scratch

  char* ws = (char*)d_ws;
  bf16_t* hb = (bf16_t*)ws;                 // [N][256] bf16            3,145,728 B
  bf16_t* Wt = (bf16_t*)(ws + 3145728);     // [3][H][64][256] bf16       393,216 B
  bf16_t* Qb = (bf16_t*)(ws + 3538944);     // [H][N][64] bf16 (scaled) 3,145,728 B
  bf16_t* Kf = (bf16_t*)(ws + 6684672);     // [H] K fragments          3,145,728 B
  bf16_t* Vf = (bf16_t*)(ws + 9830400);     // [H] V fragments          3,145,728 B

  prep_kernel<<<1024, 256, 0, stream>>>(h, WQ, WK, WV, hb, Wt);
  proj_kernel<<<dim3(96, 4), 256, 0, stream>>>(hb, Wt, bQ, bK, bV, Qb, Kf, Vf);
  attn_kernel<<<768, 256, 0, stream>>>(adj, Qb, Kf, Vf, out);
}

// Round 14
// 159.800 us; speedup vs baseline: 1.3656x; 1.0068x over previous
//
#include <hip/hip_runtime.h>
#include <hip/hip_bf16.h>

#define NN 6144
#define HEADS 4
#define DIN 256
#define DOUT 64

typedef __bf16 bf16_t;
typedef bf16_t bf16x8 __attribute__((ext_vector_type(8)));
typedef float f32x16 __attribute__((ext_vector_type(16)));
typedef float f32x4 __attribute__((ext_vector_type(4)));
typedef unsigned u32x4 __attribute__((ext_vector_type(4)));

#if __has_builtin(__builtin_amdgcn_exp2f)
#define EXP2(x) __builtin_amdgcn_exp2f(x)
#else
#define EXP2(x) exp2f(x)
#endif

static __device__ __forceinline__ f32x16 zero16() {
  f32x16 z;
#pragma unroll
  for (int i = 0; i < 16; ++i) z[i] = 0.0f;
  return z;
}

static __device__ __forceinline__ bf16x8 ldg8(const bf16_t* p) {
  return *reinterpret_cast<const bf16x8*>(p);
}

// pack two f32 -> one u32 of 2 bf16 (element 0 in low half)
static __device__ __forceinline__ unsigned pk2(float a, float b) {
  union { bf16_t h[2]; unsigned u; } z;
  z.h[0] = (bf16_t)a;
  z.h[1] = (bf16_t)b;
  return z.u;
}

// v_permlane32_swap_b32: x.hi32lanes <-> y.lo32lanes
static __device__ __forceinline__ void pswap(unsigned& x, unsigned& y) {
  asm("v_permlane32_swap_b32 %0, %1" : "+v"(x), "+v"(y));
}

// non-temporal 16B read (read-once adj stream; don't evict K/V from L2)
static __device__ __forceinline__ f32x4 ldnt4(const float* p) {
  return __builtin_nontemporal_load(reinterpret_cast<const f32x4*>(p));
}

#define SCHED0() __builtin_amdgcn_sched_barrier(0)
#define VW(N)                                                   \
  asm volatile("s_waitcnt vmcnt(" #N ")" ::: "memory");         \
  SCHED0();

// ---------------- prep: h->bf16, W->bf16^T (Q-scale folded), zero out+denom
__global__ __launch_bounds__(256) void prep_kernel(
    const float* __restrict__ h, const float* __restrict__ WQ,
    const float* __restrict__ WK, const float* __restrict__ WV,
    bf16_t* __restrict__ hb, bf16_t* __restrict__ Wt,
    float* __restrict__ out, float* __restrict__ denom) {
  int stride = gridDim.x * blockDim.x;
  int idx = blockIdx.x * blockDim.x + threadIdx.x;
  for (int i = idx; i < HEADS * NN * DOUT; i += stride) out[i] = 0.0f;
  for (int i = idx; i < HEADS * NN; i += stride) denom[i] = 0.0f;
  for (int i = idx; i < NN * DIN; i += stride) hb[i] = (bf16_t)h[i];
  const float c2 = 0.0625f * 1.4426950408889634f;  // (1/sqrt(256)) * log2(e)
  for (int i = idx; i < 3 * HEADS * DOUT * DIN; i += stride) {
    int d = i & (DIN - 1);
    int o = (i >> 8) & (DOUT - 1);
    int hh = (i >> 14) & (HEADS - 1);
    int m = i >> 16;
    const float* W = (m == 0) ? WQ : (m == 1) ? WK : WV;
    float v = W[(hh * DIN + d) * DOUT + o];
    if (m == 0) v *= c2;
    Wt[i] = (bf16_t)v;  // Wt[m][hh][o][d]
  }
}

// ---------------- proj: Qb row-major [H][N][64]; Kf/Vf in MFMA-fragment order.
__global__ __launch_bounds__(256) void proj_kernel(
    const bf16_t* __restrict__ hb, const bf16_t* __restrict__ Wt,
    const float* __restrict__ bQ, const float* __restrict__ bK,
    const float* __restrict__ bV,
    bf16_t* __restrict__ Qb, bf16_t* __restrict__ Kf, bf16_t* __restrict__ Vf) {
  const float c2 = 0.0625f * 1.4426950408889634f;
  int tid = threadIdx.x;
  int w = tid >> 6, l = tid & 63;
  int l31 = l & 31, lh = l >> 5;
  int hh = blockIdx.y;
  int n0 = blockIdx.x * 64;

#pragma unroll
  for (int s = 0; s < 3; ++s) {
    int t = w * 3 + s;  // 12 tiles: 0-3 Q, 4-7 K, 8-11 V
    if (t < 8) {
      int m = t >> 2;            // 0=Q, 1=K
      int rh = (t >> 1) & 1;     // row half (key half)
      int oh = t & 1;            // out-col half
      const bf16_t* arow = hb + (n0 + rh * 32 + l31) * DIN + 8 * lh;
      const bf16_t* brow = Wt + ((m * HEADS + hh) * DOUT + oh * 32 + l31) * DIN + 8 * lh;
      f32x16 acc = zero16();
#pragma unroll
      for (int kc = 0; kc < 16; ++kc)
        acc = __builtin_amdgcn_mfma_f32_32x32x16_bf16(ldg8(arow + kc * 16),
                                                      ldg8(brow + kc * 16), acc, 0, 0, 0);
      const float* bias = (m == 0) ? bQ : bK;
      float bv = bias[hh * DOUT + oh * 32 + l31];
      if (m == 0) {
        bv *= c2;
        bf16_t* outp = Qb + (size_t)(hh * NN + n0 + rh * 32) * DOUT + oh * 32 + l31;
#pragma unroll
        for (int r = 0; r < 16; ++r) {
          int q = (r & 3) + 8 * (r >> 2) + 4 * lh;
          outp[q * DOUT] = (bf16_t)(acc[r] + bv);
        }
      } else {
        int o = oh * 32 + l31;
        bf16_t* outp = Kf + (size_t)hh * 393216 + (n0 >> 6) * 4096 + rh * 2048 +
                       (o >> 4) * 512 + ((o >> 3) & 1) * 256 + (o & 7);
#pragma unroll
        for (int r = 0; r < 16; ++r) {
          int rr = (r & 3) + 8 * (r >> 2) + 4 * lh;  // key & 31
          outp[rr * 8] = (bf16_t)(acc[r] + bv);
        }
      }
    } else {
      int tt = t - 8;
      int oh = tt >> 1, nh = tt & 1;  // oh = d half, nh = key half
      const bf16_t* arow = Wt + ((2 * HEADS + hh) * DOUT + oh * 32 + l31) * DIN + 8 * lh;
      const bf16_t* brow = hb + (n0 + nh * 32 + l31) * DIN + 8 * lh;
      f32x16 acc = zero16();
#pragma unroll
      for (int kc = 0; kc < 16; ++kc)
        acc = __builtin_amdgcn_mfma_f32_32x32x16_bf16(ldg8(arow + kc * 16),
                                                      ldg8(brow + kc * 16), acc, 0, 0, 0);
      int k6 = nh * 32 + l31;
      bf16_t* outp = Vf + (size_t)hh * 393216 + (n0 >> 6) * 4096 + oh * 2048 +
                     (k6 >> 4) * 512 + ((k6 >> 3) & 1) * 256 + (k6 & 7);
#pragma unroll
      for (int r = 0; r < 16; ++r) {
        int rr = (r & 3) + 8 * (r >> 2) + 4 * lh;  // d & 31
        float bvv = bV[hh * DOUT + oh * 32 + rr];
        outp[rr * 8] = (bf16_t)(acc[r] + bvv);
      }
    }
  }
}

// one iteration body (12-tile KSPLIT version). AIN = regs holding tile IT+1;
// AOUT = regs receiving tile IT+2. CUR = LDS buffer parity.
// vmcnt ledger: entry IN(8); +KV(16); +OUT(8). Compiler's vf wait = vmcnt(8)
// leaves OUT in flight; explicit VW(8) drains IN before its ds_write.
#define ATTN_BODY(AIN, AOUT, IT, CUR)                                          \
  {                                                                            \
    int tc = t0 + (IT);                                                        \
    if (tc >= 12) tc -= 12;                                                    \
    int tni = t0 + (IT) + 2;                                                   \
    if (tni >= 12) tni -= 12;                                                  \
    if (tni >= 12) tni -= 12;                                                  \
    int chunk = ckb + tc * 4 + w;                                              \
    const bf16_t* kbase = Kh + (size_t)chunk * 4096 + l * 8;                   \
    const bf16_t* vbase = Vh + (size_t)chunk * 4096 + l * 8;                   \
    bf16x8 kf[8], vf[8];                                                       \
    _Pragma("unroll") for (int x = 0; x < 4; ++x) {                            \
      kf[x] = ldg8(kbase + x * 512);                                           \
      kf[4 + x] = ldg8(kbase + 2048 + x * 512);                                \
    }                                                                          \
    _Pragma("unroll") for (int x = 0; x < 4; ++x) {                            \
      vf[x] = ldg8(vbase + x * 512);                                           \
      vf[4 + x] = ldg8(vbase + 2048 + x * 512);                                \
    }                                                                          \
    SCHED0();                                                                  \
    if ((IT) < 10) { /* issue tile IT+2 */                                     \
      _Pragma("unroll") for (int i = 0; i < 8; ++i) {                          \
        int row = 8 * w + i;                                                   \
        AOUT[i] = ldnt4(adjq + (size_t)row * NN + tni * 256 + ((l ^ i) << 2)); \
      }                                                                        \
    }                                                                          \
    SCHED0();                                                                  \
    f32x4 av[8];                                                               \
    _Pragma("unroll") for (int t2 = 0; t2 < 2; ++t2)                           \
        _Pragma("unroll") for (int g = 0; g < 4; ++g) {                        \
      int c = 16 * w + 8 * t2 + 2 * g + lh;                                    \
      av[t2 * 4 + g] = *reinterpret_cast<const f32x4*>(                        \
          &smem[CUR][l31][(c ^ (l31 & 7)) << 2]);                              \
    }                                                                          \
    f32x16 s0 = zero16(), s1 = zero16();                                       \
    _Pragma("unroll") for (int kc = 0; kc < 4; ++kc) {                         \
      s0 = __builtin_amdgcn_mfma_f32_32x32x16_bf16(kf[kc], qf[kc], s0, 0, 0, 0);\
      s1 = __builtin_amdgcn_mfma_f32_32x32x16_bf16(kf[4 + kc], qf[kc], s1, 0, 0, 0);\
    }                                                                          \
    _Pragma("unroll") for (int t2 = 0; t2 < 2; ++t2) {                         \
      f32x16 st = t2 ? s1 : s0;                                                \
      float p[16];                                                             \
      _Pragma("unroll") for (int r = 0; r < 16; ++r) {                         \
        float pv = EXP2(st[r] * av[4 * t2 + (r >> 2)][r & 3]);                 \
        p[r] = pv;                                                             \
        sacc += pv;                                                            \
      }                                                                        \
      _Pragma("unroll") for (int c2 = 0; c2 < 2; ++c2) {                       \
        unsigned wA0 = pk2(p[8 * c2 + 0], p[8 * c2 + 1]);                      \
        unsigned wB0 = pk2(p[8 * c2 + 2], p[8 * c2 + 3]);                      \
        unsigned wA1 = pk2(p[8 * c2 + 4], p[8 * c2 + 5]);                      \
        unsigned wB1 = pk2(p[8 * c2 + 6], p[8 * c2 + 7]);                      \
        pswap(wA0, wA1);                                                       \
        pswap(wB0, wB1);                                                       \
        u32x4 pw;                                                              \
        pw[0] = wA0; pw[1] = wB0; pw[2] = wA1; pw[3] = wB1;                    \
        bf16x8 pb = __builtin_bit_cast(bf16x8, pw);                            \
        int kc = 2 * t2 + c2;                                                  \
        o0 = __builtin_amdgcn_mfma_f32_32x32x16_bf16(vf[kc], pb, o0, 0, 0, 0); \
        o1 = __builtin_amdgcn_mfma_f32_32x32x16_bf16(vf[4 + kc], pb, o1, 0, 0, 0);\
      }                                                                        \
    }                                                                          \
    if ((IT) < 11) { /* drain IN (tile IT+1), publish to buf[CUR^1] */         \
      VW(8)                                                                    \
      _Pragma("unroll") for (int i = 0; i < 8; ++i) {                          \
        int row = 8 * w + i;                                                   \
        *reinterpret_cast<f32x4*>(&smem[(CUR) ^ 1][row][l << 2]) = AIN[i];     \
      }                                                                        \
      asm volatile("s_waitcnt lgkmcnt(0)" ::: "memory");                       \
      SCHED0();                                                                \
      __builtin_amdgcn_s_barrier();                                           \
      SCHED0();                                                                \
    }                                                                          \
  }

// ---------------- attention: r13 pipeline, KSPLIT=2 -> 1536 blocks = EXACTLY
// 3 residency rounds at 2 blocks/CU (removes the 1.5-round tail). XCD x owns
// (head, key-half) = (x>>1, x&1): K/V 1.5 MB L2-resident. Partials combined
// via atomicAdd (no-max softmax => additive).
__global__ __launch_bounds__(256, 2) void attn_kernel(
    const float* __restrict__ adj, const bf16_t* __restrict__ Qb,
    const bf16_t* __restrict__ Kf, const bf16_t* __restrict__ Vf,
    float* __restrict__ out, float* __restrict__ denom) {
  __shared__ __align__(16) float smem[2][32][256];  // 64 KB; reused for epilogue

  int tid = threadIdx.x;
  int w = tid >> 6, l = tid & 63;
  int l31 = l & 31, lh = l >> 5;

  int bid = blockIdx.x;
  int x = bid & 7;          // XCD
  int hh = x >> 1;          // head
  int ky = x & 1;           // key half
  int qt = bid >> 3;        // q-tile 0..191
  int q0 = qt * 32;
  int t0 = qt % 12;         // column-phase rotation within the half
  const int ckb = ky * 48;  // first 64-key chunk of this half

  // Q as B-fragment: col = q = l31, k = kc*16 + 8*lh + 0..7  (pre-scaled by c2)
  const bf16_t* Qrow = Qb + (size_t)(hh * NN + q0 + l31) * DOUT + 8 * lh;
  bf16x8 qf[4];
#pragma unroll
  for (int kc = 0; kc < 4; ++kc) qf[kc] = ldg8(Qrow + kc * 16);

  const bf16_t* Kh = Kf + (size_t)hh * 393216;
  const bf16_t* Vh = Vf + (size_t)hh * 393216;
  const float* adjq = adj + (size_t)hh * NN * NN + (size_t)q0 * NN + ky * 3072;

  f32x16 o0 = zero16(), o1 = zero16();
  float sacc = 0.0f;

  f32x4 aregA[8], aregB[8];

  // ---- prologue: issue tiles t0 -> A and t0+1 -> B; drain A only; write A
  // to LDS buf0 (swizzle on write: LDS[row][u] = G[row][u^(row&7)]).
#pragma unroll
  for (int i = 0; i < 8; ++i) {
    int row = 8 * w + i;
    aregA[i] = ldnt4(adjq + (size_t)row * NN + t0 * 256 + ((l ^ i) << 2));
  }
  int t1 = t0 + 1;
  if (t1 >= 12) t1 -= 12;
#pragma unroll
  for (int i = 0; i < 8; ++i) {
    int row = 8 * w + i;
    aregB[i] = ldnt4(adjq + (size_t)row * NN + t1 * 256 + ((l ^ i) << 2));
  }
  VW(8)  // aregA landed (8 newer = aregB still in flight)
#pragma unroll
  for (int i = 0; i < 8; ++i) {
    int row = 8 * w + i;
    *reinterpret_cast<f32x4*>(&smem[0][row][l << 2]) = aregA[i];
  }
  asm volatile("s_waitcnt lgkmcnt(0)" ::: "memory");
  SCHED0();
  __builtin_amdgcn_s_barrier();
  SCHED0();

  for (int it2 = 0; it2 < 6; ++it2) {
    ATTN_BODY(aregB, aregA, 2 * it2, 0)
    ATTN_BODY(aregA, aregB, 2 * it2 + 1, 1)
  }

  VW(0)
  __syncthreads();

  // ---- epilogue: cross-wave combine in LDS (pad-33 transpose -> d-major),
  // then coalesced atomicAdd partials into out/denom.
  float stot = sacc + __shfl_xor(sacc, 32);
  float* opart = &smem[0][0][0];          // [4][64][33]
  float* ssum = opart + 4 * 64 * 33;      // [4][32]
  if (l < 32) ssum[w * 32 + l31] = stot;
#pragma unroll
  for (int r = 0; r < 16; ++r) {
    int d = (r & 3) + 8 * (r >> 2) + 4 * lh;
    opart[w * 2112 + d * 33 + l31] = o0[r];
    opart[w * 2112 + (32 + d) * 33 + l31] = o1[r];
  }
  __syncthreads();

  if (tid < 32)
    atomicAdd(&denom[hh * NN + q0 + tid],
              ssum[tid] + ssum[32 + tid] + ssum[64 + tid] + ssum[96 + tid]);
#pragma unroll
  for (int k = 0; k < 8; ++k) {
    int idx = k * 256 + tid;
    int d = idx & 63, q = idx >> 6;  // consecutive tids -> consecutive d
    float ov = opart[d * 33 + q] + opart[2112 + d * 33 + q] +
               opart[4224 + d * 33 + q] + opart[6336 + d * 33 + q];
    atomicAdd(&out[(size_t)(hh * NN + q0 + q) * DOUT + d], ov);
  }
}

// ---------------- normalize: out /= denom, float4, exact coverage
// 1536 blocks x 256 threads x 4 floats = 1,572,864 = HEADS*NN*DOUT exactly.
__global__ __launch_bounds__(256) void norm_kernel(
    float* __restrict__ out, const float* __restrict__ denom) {
  int i = blockIdx.x * 256 + threadIdx.x;  // float4 index
  float dn = denom[i >> 4];                // same q for all 4 elements
  f32x4 v = reinterpret_cast<f32x4*>(out)[i];
  float inv = 1.0f / dn;
#pragma unroll
  for (int j = 0; j < 4; ++j) v[j] *= inv;
  reinterpret_cast<f32x4*>(out)[i] = v;
}

extern "C" void kernel_launch(void* const* d_in, const int* in_sizes, int n_in,
                              void* d_out, int out_size, void* d_ws, size_t ws_size,
                              hipStream_t stream) {
  const float* adj = (const float*)d_in[0];
  const float* h   = (const float*)d_in[1];
  const float* WQ  = (const float*)d_in[2];
  const float* bQ  = (const float*)d_in[3];
  const float* WK  = (const float*)d_in[4];
  const float* bK  = (const float*)d_in[5];
  const float* WV  = (const float*)d_in[6];
  const float* bV  = (const float*)d_in[7];
  float* out = (float*)d_out;

  if (ws_size < 13074432) return;  // ~12.5 MB scratch

  char* ws = (char*)d_ws;
  bf16_t* hb    = (bf16_t*)ws;                 // [N][256] bf16           3,145,728 B
  bf16_t* Wt    = (bf16_t*)(ws + 3145728);     // [3][H][64][256] bf16      393,216 B
  bf16_t* Qb    = (bf16_t*)(ws + 3538944);     // [H][N][64] bf16 (scaled)3,145,728 B
  bf16_t* Kf    = (bf16_t*)(ws + 6684672);     // [H] K fragments         3,145,728 B
  bf16_t* Vf    = (bf16_t*)(ws + 9830400);     // [H] V fragments         3,145,728 B
  float*  denom = (float*)(ws + 12976128);     // [H][N] f32                 98,304 B

  prep_kernel<<<1024, 256, 0, stream>>>(h, WQ, WK, WV, hb, Wt, out, denom);
  proj_kernel<<<dim3(96, 4), 256, 0, stream>>>(hb, Wt, bQ, bK, bV, Qb, Kf, Vf);
  attn_kernel<<<1536, 256, 0, stream>>>(adj, Qb, Kf, Vf, out, denom);
  norm_kernel<<<1536, 256, 0, stream>>>(out, denom);
}